// Round 5
// baseline (1114.288 us; speedup 1.0000x reference)
//
#include <hip/hip_runtime.h>
#include <hip/hip_bf16.h>
#include <math.h>

#define HW 4096
typedef __hip_bfloat16 bf16;
typedef __attribute__((ext_vector_type(8))) short bfrag;
typedef __attribute__((ext_vector_type(4))) float ffrag;

__device__ __forceinline__ float bf2f(short u) {
    return __uint_as_float(((unsigned)(unsigned short)u) << 16);
}
__device__ __forceinline__ short f2bfs(float v) {
    bf16 h = __float2bfloat16(v);
    return *reinterpret_cast<short*>(&h);
}

// ======================= cast + transpose x: [256][4096] -> [4096][256] bf16 ==========
__global__ __launch_bounds__(256) void cast_xt(const float* __restrict__ x, bf16* __restrict__ xt)
{
    __shared__ float t[64][65];
    int b = blockIdx.z, it = blockIdx.y, pt = blockIdx.x;
    int ic0 = it * 64, px0 = pt * 64;
    int tid = threadIdx.x;
    for (int l = 0; l < 16; l++) {
        int e = tid + l * 256;
        int px = e & 63, ic = e >> 6;
        t[ic][px] = x[((long)b * 256 + ic0 + ic) * HW + px0 + px];
    }
    __syncthreads();
    for (int l = 0; l < 16; l++) {
        int e = tid + l * 256;
        int ic = e & 63, px = e >> 6;
        xt[((long)b * HW + px0 + px) * 256 + ic0 + ic] = __float2bfloat16(t[ic][px]);
    }
}

// ======================= weight casts ==========
__global__ __launch_bounds__(256) void castw(
    const float* __restrict__ wq, const float* __restrict__ wk, const float* __restrict__ wv,
    const float* __restrict__ sq, const float* __restrict__ sk, const float* __restrict__ sv,
    const float* __restrict__ bq, const float* __restrict__ bk, const float* __restrict__ bv,
    const float* __restrict__ w_pw, const float* __restrict__ w_proj,
    bf16* __restrict__ Wall, bf16* __restrict__ wpw_bf, bf16* __restrict__ wproj_bf,
    float* __restrict__ sb_s, float* __restrict__ sb_b)
{
    int idx = blockIdx.x * 256 + threadIdx.x;
    if (idx < 262144) {
        int oc = idx >> 8, i = idx & 255;
        float v;
        if (oc < 256) v = wq[oc * 256 + i];
        else if (oc < 512) v = wk[(oc - 256) * 256 + i];
        else v = wv[(oc - 512) * 256 + i];
        Wall[idx] = __float2bfloat16(v);
        return;
    }
    idx -= 262144;
    if (idx < 262144) { wpw_bf[idx] = __float2bfloat16(w_pw[idx]); return; }
    idx -= 262144;
    if (idx < 131072) { wproj_bf[idx] = __float2bfloat16(w_proj[idx]); return; }
    idx -= 131072;
    if (idx < 1024) {
        int oc = idx;
        float s, bb;
        if (oc < 256) { s = sq[oc]; bb = bq[oc]; }
        else if (oc < 512) { s = sk[oc - 256]; bb = bk[oc - 256]; }
        else { s = sv[oc - 512]; bb = bv[oc - 512]; }
        sb_s[oc] = s; sb_b[oc] = bb;
    }
}

// ======================= MFMA qkv GEMM (reg-prefetch pipeline) ==========
__global__ __launch_bounds__(256) void mfma_qkv(
    const bf16* __restrict__ Xt, const bf16* __restrict__ Wall,
    const float* __restrict__ sb_s, const float* __restrict__ sb_b,
    bf16* __restrict__ qkv0)
{
    __shared__ __align__(16) short As[128 * 40];
    __shared__ __align__(16) short Bs[128 * 40];
    int b = blockIdx.z, mt = blockIdx.y, nt = blockIdx.x;
    int oc0 = mt * 128, n0 = nt * 128;
    int tid = threadIdx.x;
    int lane = tid & 63, wave = tid >> 6;
    int lr = lane & 15, quad = lane >> 4;
    int wm = (wave & 1) * 64, wn = (wave >> 1) * 64;
    ffrag acc[4][4];
#pragma unroll
    for (int i = 0; i < 4; i++)
#pragma unroll
        for (int j = 0; j < 4; j++)
#pragma unroll
            for (int r = 0; r < 4; r++) acc[i][j][r] = 0.f;

    int4 apf[2], bpf[2];
#pragma unroll
    for (int l = 0; l < 2; l++) {
        int e = tid + l * 256;
        int r = e >> 2, c = e & 3;
        apf[l] = *(const int4*)&Wall[(long)(oc0 + r) * 256 + c * 8];
        bpf[l] = *(const int4*)&Xt[((long)b * HW + n0 + r) * 256 + c * 8];
    }
    for (int s = 0; s < 8; s++) {
        __syncthreads();
#pragma unroll
        for (int l = 0; l < 2; l++) {
            int e = tid + l * 256;
            int r = e >> 2, c = e & 3;
            *(int4*)&As[r * 40 + c * 8] = apf[l];
            *(int4*)&Bs[r * 40 + c * 8] = bpf[l];
        }
        __syncthreads();
        if (s < 7) {
            int k0 = (s + 1) * 32;
#pragma unroll
            for (int l = 0; l < 2; l++) {
                int e = tid + l * 256;
                int r = e >> 2, c = e & 3;
                apf[l] = *(const int4*)&Wall[(long)(oc0 + r) * 256 + k0 + c * 8];
                bpf[l] = *(const int4*)&Xt[((long)b * HW + n0 + r) * 256 + k0 + c * 8];
            }
        }
        bfrag a[4], bb[4];
#pragma unroll
        for (int i = 0; i < 4; i++) a[i]  = *(const bfrag*)&As[(wm + i * 16 + lr) * 40 + quad * 8];
#pragma unroll
        for (int j = 0; j < 4; j++) bb[j] = *(const bfrag*)&Bs[(wn + j * 16 + lr) * 40 + quad * 8];
#pragma unroll
        for (int i = 0; i < 4; i++)
#pragma unroll
            for (int j = 0; j < 4; j++)
                acc[i][j] = __builtin_amdgcn_mfma_f32_16x16x32_bf16(a[i], bb[j], acc[i][j], 0, 0, 0);
    }
#pragma unroll
    for (int i = 0; i < 4; i++)
#pragma unroll
        for (int r = 0; r < 4; r++) {
            int row = oc0 + wm + i * 16 + quad * 4 + r;
            float s = sb_s[row], bb2 = sb_b[row];
#pragma unroll
            for (int j = 0; j < 4; j++) {
                int col = n0 + wn + j * 16 + lr;
                qkv0[((long)b * 1024 + row) * HW + col] = __float2bfloat16(fmaf(s, acc[i][j][r], bb2));
            }
        }
}

// ======================= MFMA pw GEMM, M=256 tile, fused dw3x3, prefetch ==========
// grid (64 y, 1, 8 b); qkvpw[b][256][4096] bf16 (raw pre-bn)
__global__ __launch_bounds__(256) void mfma_pw_dw(
    const bf16* __restrict__ qkv0, const bf16* __restrict__ wpw_bf,
    const float* __restrict__ w_dw, const float* __restrict__ s_dw, const float* __restrict__ b_dw,
    bf16* __restrict__ qkvpw)
{
    __shared__ __align__(16) short As[256 * 40];   // 20 KB
    __shared__ __align__(16) short Bst[64 * 40];   // 5 KB, perm-n-major [o*8+ux][k]
    int b = blockIdx.z, y = blockIdx.x;
    int px0 = y * 64;
    int tid = threadIdx.x;
    int lane = tid & 63, wave = tid >> 6;
    int lr = lane & 15, quad = lane >> 4;
    int wm = wave * 64;
    int dc = tid >> 3;          // 0..31: k within slab
    int ux = tid & 7;           // 0..7:  px group of 8
    int xb = ux * 8;
    ffrag acc[4][4];
#pragma unroll
    for (int i = 0; i < 4; i++)
#pragma unroll
        for (int j = 0; j < 4; j++)
#pragma unroll
            for (int r = 0; r < 4; r++) acc[i][j][r] = 0.f;

    int4 apf[4];
    int4 midpf[3]; short lopf[3], hipf[3];
    float wdpf[9], sspf, bbpf;
    // ---- preload slab 0 ----
    {
        int k0 = 0;
#pragma unroll
        for (int l = 0; l < 4; l++) {
            int e = tid + l * 256;
            int r = e >> 2, c = e & 3;
            apf[l] = *(const int4*)&wpw_bf[(long)r * 1024 + k0 + c * 8];
        }
        int ch = k0 + dc;
        const bf16* base = qkv0 + ((long)b * 1024 + ch) * HW;
#pragma unroll
        for (int dy = 0; dy < 3; dy++) {
            int gr = y + dy - 1;
            bool vr = (gr >= 0 && gr < 64);
            int4 z = {0,0,0,0};
            midpf[dy] = vr ? *(const int4*)&base[gr * 64 + xb] : z;
            lopf[dy] = (vr && ux > 0) ? *(const short*)&base[gr * 64 + xb - 1] : (short)0;
            hipf[dy] = (vr && ux < 7) ? *(const short*)&base[gr * 64 + xb + 8] : (short)0;
        }
#pragma unroll
        for (int t = 0; t < 9; t++) wdpf[t] = w_dw[ch * 9 + t];
        sspf = s_dw[ch]; bbpf = b_dw[ch];
    }

    for (int s = 0; s < 32; s++) {
        // ---- dw compute from prefetched regs ----
        short pk[8];
        {
            float o8[8];
#pragma unroll
            for (int o = 0; o < 8; o++) o8[o] = 0.f;
#pragma unroll
            for (int dy = 0; dy < 3; dy++) {
                float w10[10];
                short m8[8];
                *(int4*)m8 = midpf[dy];
                w10[0] = bf2f(lopf[dy]);
#pragma unroll
                for (int t = 0; t < 8; t++) w10[t + 1] = bf2f(m8[t]);
                w10[9] = bf2f(hipf[dy]);
#pragma unroll
                for (int dx = 0; dx < 3; dx++) {
                    float wt = wdpf[dy * 3 + dx];
#pragma unroll
                    for (int o = 0; o < 8; o++)
                        o8[o] = fmaf(wt, w10[o + dx], o8[o]);
                }
            }
#pragma unroll
            for (int o = 0; o < 8; o++)
                pk[o] = f2bfs(fmaxf(fmaf(sspf, o8[o], bbpf), 0.f));
        }
        __syncthreads();
#pragma unroll
        for (int l = 0; l < 4; l++) {
            int e = tid + l * 256;
            int r = e >> 2, c = e & 3;
            *(int4*)&As[r * 40 + c * 8] = apf[l];
        }
#pragma unroll
        for (int o = 0; o < 8; o++)
            Bst[(o * 8 + ux) * 40 + dc] = pk[o];
        __syncthreads();
        if (s < 31) {
            int k0 = (s + 1) * 32;
#pragma unroll
            for (int l = 0; l < 4; l++) {
                int e = tid + l * 256;
                int r = e >> 2, c = e & 3;
                apf[l] = *(const int4*)&wpw_bf[(long)r * 1024 + k0 + c * 8];
            }
            int ch = k0 + dc;
            const bf16* base = qkv0 + ((long)b * 1024 + ch) * HW;
#pragma unroll
            for (int dy = 0; dy < 3; dy++) {
                int gr = y + dy - 1;
                bool vr = (gr >= 0 && gr < 64);
                int4 z = {0,0,0,0};
                midpf[dy] = vr ? *(const int4*)&base[gr * 64 + xb] : z;
                lopf[dy] = (vr && ux > 0) ? *(const short*)&base[gr * 64 + xb - 1] : (short)0;
                hipf[dy] = (vr && ux < 7) ? *(const short*)&base[gr * 64 + xb + 8] : (short)0;
            }
#pragma unroll
            for (int t = 0; t < 9; t++) wdpf[t] = w_dw[ch * 9 + t];
            sspf = s_dw[ch]; bbpf = b_dw[ch];
        }
        bfrag a[4], bb[4];
#pragma unroll
        for (int i = 0; i < 4; i++) a[i] = *(const bfrag*)&As[(wm + i * 16 + lr) * 40 + quad * 8];
#pragma unroll
        for (int j = 0; j < 4; j++) {
            int px = j * 16 + lr;
            int prow = (px & 7) * 8 + (px >> 3);
            bb[j] = *(const bfrag*)&Bst[prow * 40 + quad * 8];
        }
#pragma unroll
        for (int i = 0; i < 4; i++)
#pragma unroll
            for (int j = 0; j < 4; j++)
                acc[i][j] = __builtin_amdgcn_mfma_f32_16x16x32_bf16(a[i], bb[j], acc[i][j], 0, 0, 0);
    }
#pragma unroll
    for (int i = 0; i < 4; i++)
#pragma unroll
        for (int r = 0; r < 4; r++) {
            int row = wm + i * 16 + quad * 4 + r;
#pragma unroll
            for (int j = 0; j < 4; j++) {
                int col = px0 + j * 16 + lr;
                qkvpw[((long)b * 256 + row) * HW + col] = __float2bfloat16(acc[i][j][r]);
            }
        }
}

// ======================= MFMA proj GEMM with fused epilogue, prefetch ==========
__global__ __launch_bounds__(256) void mfma_proj(
    const bf16* __restrict__ qkv0, const bf16* __restrict__ wproj_bf,
    const float* __restrict__ outr, const float* __restrict__ outc,
    const float* __restrict__ s_proj, const float* __restrict__ b_proj,
    const bf16* __restrict__ qkvpw, const float* __restrict__ s_pw, const float* __restrict__ b_pw,
    float* __restrict__ out)
{
    __shared__ __align__(16) short As[128 * 40];
    __shared__ __align__(16) short Bst[128 * 40];   // perm-n-major
    int b = blockIdx.z, mt = blockIdx.y, nt = blockIdx.x;
    int oc0 = mt * 128, y0 = nt * 2, px0 = nt * 128;
    int tid = threadIdx.x;
    int lane = tid & 63, wave = tid >> 6;
    int lr = lane & 15, quad = lane >> 4;
    int wm = (wave & 1) * 64, wn = (wave >> 1) * 64;
    ffrag acc[4][4];
#pragma unroll
    for (int i = 0; i < 4; i++)
#pragma unroll
        for (int j = 0; j < 4; j++)
#pragma unroll
            for (int r = 0; r < 4; r++) acc[i][j][r] = 0.f;

    int4 apf[2], vpf[2];
    float ropf[2]; float4 ocpf[2][2];
#pragma unroll
    for (int l = 0; l < 2; l++) {
        int e = tid + l * 256;
        int r = e >> 2, c4 = e & 3;
        apf[l] = *(const int4*)&wproj_bf[(long)(oc0 + r) * 512 + c4 * 8];
        int cx = e & 15, c = e >> 4;
        vpf[l] = *(const int4*)&qkv0[((long)b * 1024 + 512 + c) * HW + px0 + cx * 8];
        ropf[l] = outr[((long)b * 512 + c) * 64 + y0 + (cx >> 3)];
        const float* cbase = &outc[((long)b * 512 + c) * 64 + (cx & 7) * 8];
        ocpf[l][0] = *(const float4*)&cbase[0];
        ocpf[l][1] = *(const float4*)&cbase[4];
    }
    for (int s = 0; s < 16; s++) {
        __syncthreads();
#pragma unroll
        for (int l = 0; l < 2; l++) {
            int e = tid + l * 256;
            int r = e >> 2, c4 = e & 3;
            *(int4*)&As[r * 40 + c4 * 8] = apf[l];
            int cx = e & 15, c = e >> 4;
            short v8[8];
            *(int4*)v8 = vpf[l];
            float oc8[8];
            *(float4*)&oc8[0] = ocpf[l][0];
            *(float4*)&oc8[4] = ocpf[l][1];
#pragma unroll
            for (int p = 0; p < 8; p++) {
                float val = bf2f(v8[p]) + ropf[l] + oc8[p];
                Bst[(p * 16 + cx) * 40 + c] = f2bfs(fmaxf(val, 0.f));
            }
        }
        __syncthreads();
        if (s < 15) {
            int k0 = (s + 1) * 32;
#pragma unroll
            for (int l = 0; l < 2; l++) {
                int e = tid + l * 256;
                int r = e >> 2, c4 = e & 3;
                apf[l] = *(const int4*)&wproj_bf[(long)(oc0 + r) * 512 + k0 + c4 * 8];
                int cx = e & 15, c = e >> 4;
                int dh = k0 + c;
                vpf[l] = *(const int4*)&qkv0[((long)b * 1024 + 512 + dh) * HW + px0 + cx * 8];
                ropf[l] = outr[((long)b * 512 + dh) * 64 + y0 + (cx >> 3)];
                const float* cbase = &outc[((long)b * 512 + dh) * 64 + (cx & 7) * 8];
                ocpf[l][0] = *(const float4*)&cbase[0];
                ocpf[l][1] = *(const float4*)&cbase[4];
            }
        }
        bfrag a[4], bb[4];
#pragma unroll
        for (int i = 0; i < 4; i++) a[i] = *(const bfrag*)&As[(wm + i * 16 + lr) * 40 + quad * 8];
#pragma unroll
        for (int j = 0; j < 4; j++) {
            int prow = (lr & 7) * 16 + (wn >> 3) + j * 2 + (lr >> 3);
            bb[j] = *(const bfrag*)&Bst[prow * 40 + quad * 8];
        }
#pragma unroll
        for (int i = 0; i < 4; i++)
#pragma unroll
            for (int j = 0; j < 4; j++)
                acc[i][j] = __builtin_amdgcn_mfma_f32_16x16x32_bf16(a[i], bb[j], acc[i][j], 0, 0, 0);
    }
#pragma unroll
    for (int i = 0; i < 4; i++)
#pragma unroll
        for (int r = 0; r < 4; r++) {
            int row = oc0 + wm + i * 16 + quad * 4 + r;
            float sp = s_proj[row], bp = b_proj[row];
            float sw = s_pw[row], bw = b_pw[row];
#pragma unroll
            for (int j = 0; j < 4; j++) {
                int col = px0 + wn + j * 16 + lr;
                long idx = ((long)b * 256 + row) * HW + col;
                float t = fmaf(sp, acc[i][j][r], bp);
                float m = fmaf(sw, bf2f(*(const short*)&qkvpw[idx]), bw);
                out[idx] = m / (1.f + __expf(-t));
            }
        }
}

// ======================= MFMA stripe conv 1 (A-prefetch) ==========
__global__ __launch_bounds__(256) void mstripe1(
    const bf16* __restrict__ xt, const bf16* __restrict__ Nt, const float* __restrict__ C,
    bf16* __restrict__ outp, int dir)
{
    __shared__ __align__(16) short As[64 * 264];
    int b = blockIdx.y;
    int tid = threadIdx.x;
    int wave = tid >> 6, lane = tid & 63;
    int lr = lane & 15, quad = lane >> 4;
    int y = blockIdx.x * 4 + wave;
    ffrag acc[4][4];
#pragma unroll
    for (int i = 0; i < 4; i++)
#pragma unroll
        for (int j = 0; j < 4; j++)
#pragma unroll
            for (int r = 0; r < 4; r++) acc[i][j][r] = 0.f;
    bfrag zf;
#pragma unroll
    for (int e = 0; e < 8; e++) zf[e] = 0;

    int4 apf[8];
#pragma unroll
    for (int l = 0; l < 8; l++) {
        int e = tid + l * 256;
        int oc = e >> 5, c = e & 31;
        apf[l] = *(const int4*)&Nt[(long)oc * 1792 + c * 8];
    }
    for (int d = 0; d < 7; d++) {
        __syncthreads();
#pragma unroll
        for (int l = 0; l < 8; l++) {
            int e = tid + l * 256;
            int oc = e >> 5, c = e & 31;
            *(int4*)&As[oc * 264 + c * 8] = apf[l];
        }
        __syncthreads();
        if (d < 6) {
#pragma unroll
            for (int l = 0; l < 8; l++) {
                int e = tid + l * 256;
                int oc = e >> 5, c = e & 31;
                apf[l] = *(const int4*)&Nt[(long)oc * 1792 + (d + 1) * 256 + c * 8];
            }
        }
        int off = d - 3;
        int row = y + off;
        bool vrow = (row >= 0 && row < 64);
        for (int ks = 0; ks < 8; ks++) {
            bfrag a[4], bb[4];
#pragma unroll
            for (int i = 0; i < 4; i++)
                a[i] = *(const bfrag*)&As[(i * 16 + lr) * 264 + ks * 32 + quad * 8];
#pragma unroll
            for (int j = 0; j < 4; j++) {
                int x = j * 16 + lr;
                if (dir == 0) {
                    bb[j] = vrow ? *(const bfrag*)&xt[((long)b * HW + row * 64 + x) * 256 + ks * 32 + quad * 8] : zf;
                } else {
                    int xs = x + off;
                    bb[j] = (xs >= 0 && xs < 64)
                        ? *(const bfrag*)&xt[((long)b * HW + y * 64 + xs) * 256 + ks * 32 + quad * 8] : zf;
                }
            }
#pragma unroll
            for (int i = 0; i < 4; i++)
#pragma unroll
                for (int j = 0; j < 4; j++)
                    acc[i][j] = __builtin_amdgcn_mfma_f32_16x16x32_bf16(a[i], bb[j], acc[i][j], 0, 0, 0);
        }
    }
#pragma unroll
    for (int i = 0; i < 4; i++)
#pragma unroll
        for (int r = 0; r < 4; r++) {
            int oc = i * 16 + quad * 4 + r;
#pragma unroll
            for (int j = 0; j < 4; j++) {
                int x = j * 16 + lr;
                float ct = 0.f;
                int base = dir ? x : y;
                for (int d = 0; d < 7; d++) {
                    int t = base + d - 3;
                    if (t >= 0 && t < 64) ct += C[d * 64 + oc];
                }
                outp[((long)b * 64 + oc) * HW + y * 64 + x] = __float2bfloat16(acc[i][j][r] + ct);
            }
        }
}

// ======================= MFMA stripe conv 2, both dirs, prefetch ==========
__device__ __forceinline__ void ms2_load(
    int t, int b, int y0, int oc0, int tid,
    const bf16* __restrict__ x1a, const bf16* __restrict__ x3a,
    const bf16* __restrict__ Mv, const bf16* __restrict__ Mh,
    int4* apf, short bpf[2][8])
{
    int dir = t / 14, rem = t - dir * 14, d = rem >> 1, ks = rem & 1;
    const bf16* inp = dir ? x3a : x1a;
    const bf16* Mt  = dir ? Mh  : Mv;
    int off = d - 3;
#pragma unroll
    for (int l = 0; l < 2; l++) {
        int e = tid + l * 256;
        int r = e >> 2, c4 = e & 3;
        apf[l] = *(const int4*)&Mt[(long)(oc0 + r) * 448 + d * 64 + ks * 32 + c4 * 8];
        int cx = e & 15, c = e >> 4;
        int ic = ks * 32 + c;
        const bf16* src = &inp[((long)b * 64 + ic) * HW];
        if (dir == 0) {
            int srow = y0 + (cx >> 3) + off;
            if (srow >= 0 && srow < 64)
                *(int4*)bpf[l] = *(const int4*)&src[srow * 64 + (cx & 7) * 8];
            else {
                int4 z = {0,0,0,0};
                *(int4*)bpf[l] = z;
            }
        } else {
            int row = y0 + (cx >> 3);
#pragma unroll
            for (int p = 0; p < 8; p++) {
                int xs = (cx & 7) * 8 + p + off;
                bpf[l][p] = (xs >= 0 && xs < 64) ? *(const short*)&src[row * 64 + xs] : (short)0;
            }
        }
    }
}

__global__ __launch_bounds__(256) void mstripe2(
    const bf16* __restrict__ x1a, const bf16* __restrict__ x3a,
    const bf16* __restrict__ Mv, const bf16* __restrict__ Mh,
    bf16* __restrict__ qkvpw)
{
    __shared__ __align__(16) short As[128 * 40];
    __shared__ __align__(16) short Bst[128 * 40];
    int b = blockIdx.z, mt = blockIdx.y, nt = blockIdx.x;
    int oc0 = mt * 128, y0 = nt * 2, px0 = nt * 128;
    int tid = threadIdx.x;
    int lane = tid & 63, wave = tid >> 6;
    int lr = lane & 15, quad = lane >> 4;
    int wm = (wave & 1) * 64, wn = (wave >> 1) * 64;
    ffrag acc[4][4];
#pragma unroll
    for (int i = 0; i < 4; i++)
#pragma unroll
        for (int j = 0; j < 4; j++)
#pragma unroll
            for (int r = 0; r < 4; r++) acc[i][j][r] = 0.f;

    int4 apf[2]; short bpf[2][8];
    ms2_load(0, b, y0, oc0, tid, x1a, x3a, Mv, Mh, apf, bpf);
    for (int t = 0; t < 28; t++) {
        __syncthreads();
#pragma unroll
        for (int l = 0; l < 2; l++) {
            int e = tid + l * 256;
            int r = e >> 2, c4 = e & 3;
            *(int4*)&As[r * 40 + c4 * 8] = apf[l];
            int cx = e & 15, c = e >> 4;
#pragma unroll
            for (int p = 0; p < 8; p++)
                Bst[(p * 16 + cx) * 40 + c] = bpf[l][p];
        }
        __syncthreads();
        if (t < 27)
            ms2_load(t + 1, b, y0, oc0, tid, x1a, x3a, Mv, Mh, apf, bpf);
        bfrag a[4], bb[4];
#pragma unroll
        for (int i = 0; i < 4; i++) a[i] = *(const bfrag*)&As[(wm + i * 16 + lr) * 40 + quad * 8];
#pragma unroll
        for (int j = 0; j < 4; j++) {
            int prow = (lr & 7) * 16 + (wn >> 3) + j * 2 + (lr >> 3);
            bb[j] = *(const bfrag*)&Bst[prow * 40 + quad * 8];
        }
#pragma unroll
        for (int i = 0; i < 4; i++)
#pragma unroll
            for (int j = 0; j < 4; j++)
                acc[i][j] = __builtin_amdgcn_mfma_f32_16x16x32_bf16(a[i], bb[j], acc[i][j], 0, 0, 0);
    }
#pragma unroll
    for (int i = 0; i < 4; i++)
#pragma unroll
        for (int r = 0; r < 4; r++) {
            int row = oc0 + wm + i * 16 + quad * 4 + r;
#pragma unroll
            for (int j = 0; j < 4; j++) {
                int col = px0 + wn + j * 16 + lr;
                long idx = ((long)b * 256 + row) * HW + col;
                float v = bf2f(*(const short*)&qkvpw[idx]) + acc[i][j][r];
                qkvpw[idx] = __float2bfloat16(v);
            }
        }
}

// ======================= act_dn (bf16, register-resident, both tensors) ==========
__global__ __launch_bounds__(256) void softmax_sp_bf(bf16* __restrict__ x1, bf16* __restrict__ x3)
{
    __shared__ float red[4];
    int bc = blockIdx.x;   // 0..1023
    bf16* p = (bc < 512) ? (x1 + (long)bc * HW) : (x3 + (long)(bc - 512) * HW);
    int tid = threadIdx.x;
    float v[16];
#pragma unroll
    for (int i = 0; i < 16; i++) v[i] = __bfloat162float(p[tid + i * 256]);
    float m = -1e30f;
#pragma unroll
    for (int i = 0; i < 16; i++) m = fmaxf(m, v[i]);
    for (int o = 32; o > 0; o >>= 1) m = fmaxf(m, __shfl_down(m, o));
    if ((tid & 63) == 0) red[tid >> 6] = m;
    __syncthreads();
    m = fmaxf(fmaxf(red[0], red[1]), fmaxf(red[2], red[3]));
    __syncthreads();
    float z = 0.f;
#pragma unroll
    for (int i = 0; i < 16; i++) { v[i] = __expf(v[i] - m); z += v[i]; }
    for (int o = 32; o > 0; o >>= 1) z += __shfl_down(z, o);
    if ((tid & 63) == 0) red[tid >> 6] = z;
    __syncthreads();
    z = red[0] + red[1] + red[2] + red[3];
    float inv = 1.f / z;
#pragma unroll
    for (int i = 0; i < 16; i++) p[tid + i * 256] = __float2bfloat16(v[i] * inv);
}

__global__ __launch_bounds__(256) void group_renorm_bf(bf16* __restrict__ x1, bf16* __restrict__ x3)
{
    int which = blockIdx.x >> 10;
    long t = (long)(blockIdx.x & 1023) * 256 + threadIdx.x;   // B*8*4096
    bf16* x = which ? x3 : x1;
    int s = (int)(t & 4095);
    int h = (int)((t >> 12) & 7);
    int b = (int)(t >> 15);
    bf16* base = x + (((long)(b * 64 + h * 8)) << 12) + s;
    float v[8]; float g = 0.f;
#pragma unroll
    for (int j = 0; j < 8; j++) { v[j] = __bfloat162float(base[(long)j << 12]); g += v[j]; }
    float inv = 1.f / (g + 1e-6f);
#pragma unroll
    for (int j = 0; j < 8; j++) base[(long)j << 12] = __float2bfloat16(v[j] * inv);
}

// ======================= row/col means of qkv0 (bf16) =======================
__global__ __launch_bounds__(64) void meanrc(
    const bf16* __restrict__ in, float* __restrict__ rowm, float* __restrict__ colm)
{
    __shared__ float tile[64][65];
    int bc = blockIdx.x;
    const bf16* p = in + (long)bc * HW;
    int t = threadIdx.x;
    for (int i = 0; i < 64; i++) tile[i][t] = __bfloat162float(p[i * 64 + t]);
    __syncthreads();
    float rs = 0.f, cs = 0.f;
    for (int i = 0; i < 64; i++) { rs += tile[t][i]; cs += tile[i][t]; }
    rowm[(long)bc * 64 + t] = rs * (1.f / 64.f);
    colm[(long)bc * 64 + t] = cs * (1.f / 64.f);
}

// ======================= squeeze attention =======================
__device__ __forceinline__ float interp_pe(const float* pe, int c, int i)
{
    float coord = fminf(fmaxf((i + 0.5f) * 0.25f - 0.5f, 0.f), 15.f);
    int lo = (int)coord;
    int hi = min(lo + 1, 15);
    float t = coord - (float)lo;
    return pe[c * 16 + lo] * (1.f - t) + pe[c * 16 + hi] * t;
}

__global__ __launch_bounds__(256) void attn_kernel(
    const float* __restrict__ rowm, const float* __restrict__ colm,
    const float* __restrict__ pe_rq, const float* __restrict__ pe_rk,
    const float* __restrict__ pe_cq, const float* __restrict__ pe_ck,
    float* __restrict__ outr, float* __restrict__ outc)
{
    int h = blockIdx.x, b = blockIdx.y, dir = blockIdx.z;
    const float* mean = dir ? colm : rowm;
    const float* peq = dir ? pe_cq : pe_rq;
    const float* pek = dir ? pe_ck : pe_rk;
    float* outp = (dir ? outc : outr) + ((long)b * 512 + h * 64) * 64;
    __shared__ float qs[32][64], ks[32][64], vs[64][64], S[64][66];
    int tid = threadIdx.x;

    for (int e = tid; e < 2048; e += 256) {
        int c = e >> 6, i = e & 63;
        int gc = h * 32 + c;
        qs[c][i] = mean[((long)b * 1024 + gc) * 64 + i]       + interp_pe(peq, gc, i);
        ks[c][i] = mean[((long)b * 1024 + 256 + gc) * 64 + i] + interp_pe(pek, gc, i);
    }
    for (int e = tid; e < 4096; e += 256) {
        int dc = e >> 6, j = e & 63;
        vs[dc][j] = mean[((long)b * 1024 + 512 + h * 64 + dc) * 64 + j];
    }
    __syncthreads();
    const float scl = 0.17677669529663687f;
    for (int e = tid; e < 4096; e += 256) {
        int i = e >> 6, j = e & 63;
        float s = 0.f;
#pragma unroll
        for (int c = 0; c < 32; c++) s = fmaf(qs[c][i], ks[c][j], s);
        S[i][j] = s * scl;
    }
    __syncthreads();
    if (tid < 64) {
        int i = tid;
        float m = -1e30f;
        for (int j = 0; j < 64; j++) m = fmaxf(m, S[i][j]);
        float z = 0.f;
        for (int j = 0; j < 64; j++) { float e2 = __expf(S[i][j] - m); S[i][j] = e2; z += e2; }
        float inv = 1.f / z;
        for (int j = 0; j < 64; j++) S[i][j] *= inv;
    }
    __syncthreads();
    for (int e = tid; e < 4096; e += 256) {
        int dc = e >> 6, i = e & 63;
        float o = 0.f;
#pragma unroll
        for (int j = 0; j < 64; j++) o = fmaf(S[i][j], vs[dc][j], o);
        outp[dc * 64 + i] = o;
    }
}

// ======================= small fp32 GEMM (row/col attention projections) ==========
__global__ __launch_bounds__(256) void gemm1x1(
    const void* __restrict__ X, long x_b, int in_bf16,
    const float* __restrict__ W,
    const float* __restrict__ scale, const float* __restrict__ bias,
    void* __restrict__ out, long o_b, int out_bf16,
    int OC, int IC, int NP,
    int relu_in)
{
    __shared__ __align__(16) float As[16][68];
    __shared__ __align__(16) float Bs[16][64];
    int b  = blockIdx.z;
    int oc0 = blockIdx.y * 64;
    int n0  = blockIdx.x * 64;
    int tid = threadIdx.x;
    int tx = tid & 15, ty = tid >> 4;
    float acc[4][4] = {};

    for (int k0 = 0; k0 < IC; k0 += 16) {
#pragma unroll
        for (int l = 0; l < 4; l++) {
            int e = tid + l * 256;
            int oc = e >> 4, kk = e & 15;
            As[kk][oc] = W[(long)(oc0 + oc) * IC + (k0 + kk)];
        }
#pragma unroll
        for (int l = 0; l < 4; l++) {
            int e = tid + l * 256;
            int kk = e >> 6, n = e & 63;
            int ic = k0 + kk;
            long xi = (long)b * x_b + (long)ic * NP + (n0 + n);
            float v = in_bf16 ? __bfloat162float(((const bf16*)X)[xi])
                              : ((const float*)X)[xi];
            if (relu_in) v = fmaxf(v, 0.f);
            Bs[kk][n] = v;
        }
        __syncthreads();
#pragma unroll
        for (int kk = 0; kk < 16; kk++) {
            float a[4], bv[4];
            *(float4*)a  = *(const float4*)&As[kk][ty * 4];
            *(float4*)bv = *(const float4*)&Bs[kk][tx * 4];
#pragma unroll
            for (int i = 0; i < 4; i++)
#pragma unroll
                for (int j = 0; j < 4; j++)
                    acc[i][j] = fmaf(a[i], bv[j], acc[i][j]);
        }
        __syncthreads();
    }

#pragma unroll
    for (int i = 0; i < 4; i++) {
        int oc = oc0 + ty * 4 + i;
        float s  = scale ? scale[oc] : 1.f;
        float bb = bias  ? bias[oc]  : 0.f;
#pragma unroll
        for (int j = 0; j < 4; j++) {
            int n = n0 + tx * 4 + j;
            float v = fmaf(s, acc[i][j], bb);
            long oidx = (long)b * o_b + (long)oc * NP + n;
            if (out_bf16) ((bf16*)out)[oidx] = __float2bfloat16(v);
            else          ((float*)out)[oidx] = v;
        }
    }
}

// ======================= weight pre-contraction =======================
__global__ __launch_bounds__(256) void build_wga(
    const float* __restrict__ wq, const float* __restrict__ wk, const float* __restrict__ wv,
    const float* __restrict__ sq, const float* __restrict__ sk, const float* __restrict__ sv,
    const float* __restrict__ bq, const float* __restrict__ bk, const float* __restrict__ bv,
    const float* __restrict__ cov_s, const float* __restrict__ cov_b,
    float* __restrict__ Wga, float* __restrict__ beta)
{
    int idx = blockIdx.x * 256 + threadIdx.x;
    int ic = idx >> 8, i = idx & 255;
    const float* Wp; float sth, bth;
    if (ic < 256)      { Wp = wq + ic * 256;         sth = sq[ic];       bth = bq[ic]; }
    else if (ic < 512) { Wp = wk + (ic - 256) * 256; sth = sk[ic - 256]; bth = bk[ic - 256]; }
    else               { Wp = wv + (ic - 512) * 256; sth = sv[ic - 512]; bth = bv[ic - 512]; }
    Wga[idx] = cov_s[ic] * sth * Wp[i];
    if (i == 0) beta[ic] = cov_s[ic] * bth + cov_b[ic];
}

// N_t[oc][d*256 + i] = sum_ic kv[oc, ic, d] * Wga[ic, i] ; grid (448, 2)
__global__ __launch_bounds__(256) void build_N(
    const float* __restrict__ kva, const float* __restrict__ kvb,
    const float* __restrict__ Wga, bf16* __restrict__ Nta, bf16* __restrict__ Ntb)
{
    const float* kvw = blockIdx.y ? kvb : kva;
    bf16* Nt = blockIdx.y ? Ntb : Nta;
    int d = blockIdx.x >> 6, oc = blockIdx.x & 63;
    int i = threadIdx.x;
    float a0 = 0.f, a1 = 0.f, a2 = 0.f, a3 = 0.f;
    for (int ic = 0; ic < 1024; ic += 4) {
        a0 = fmaf(kvw[oc * 7168 + ic * 7 + d],           Wga[ic * 256 + i],           a0);
        a1 = fmaf(kvw[oc * 7168 + (ic + 1) * 7 + d],     Wga[(ic + 1) * 256 + i],     a1);
        a2 = fmaf(kvw[oc * 7168 + (ic + 2) * 7 + d],     Wga[(ic + 2) * 256 + i],     a2);
        a3 = fmaf(kvw[oc * 7168 + (ic + 3) * 7 + d],     Wga[(ic + 3) * 256 + i],     a3);
    }
    Nt[(long)oc * 1792 + d * 256 + i] = __float2bfloat16((a0 + a1) + (a2 + a3));
}

// grid (7, 2)
__global__ __launch_bounds__(64) void build_C(
    const float* __restrict__ kva, const float* __restrict__ kvb,
    const float* __restrict__ beta, float* __restrict__ Ca, float* __restrict__ Cb)
{
    const float* kvw = blockIdx.y ? kvb : kva;
    float* C = blockIdx.y ? Cb : Ca;
    int d = blockIdx.x, oc = threadIdx.x;
    float a = 0.f;
    for (int ic = 0; ic < 1024; ic++)
        a = fmaf(kvw[oc * 7168 + ic * 7 + d], beta[ic], a);
    C[d * 64 + oc] = a;
}

// kvT2[c2][d*64+ic] = kv[ic][c2][d] ; grid (1792, 2)
__global__ __launch_bounds__(256) void kv_transpose(
    const float* __restrict__ kva, const float* __restrict__ kvb,
    float* __restrict__ kvT2a, float* __restrict__ kvT2b)
{
    const float* kvw = blockIdx.y ? kvb : kva;
    float* kvT2 = blockIdx.y ? kvT2b : kvT2a;
    int idx = blockIdx.x * 256 + threadIdx.x;
    if (idx >= 458752) return;
    int c2 = idx / 448;
    int rem = idx - c2 * 448;
    int d = rem >> 6, ic = rem & 63;
    kvT2[idx] = kvw[ic * 7168 + c2 * 7 + d];
}

// M_t[o][d*64 + ic] = sum_c2 wpw[o][c2] * kvT2[c2][d*64+ic] ; grid (448, 2)
__global__ __launch_bounds__(256) void build_M2(
    const float* __restrict__ wpw,
    const float* __restrict__ kvT2a, const float* __restrict__ kvT2b,
    bf16* __restrict__ Mta, bf16* __restrict__ Mtb)
{
    const float* kvT2 = blockIdx.y ? kvT2b : kvT2a;
    bf16* Mt = blockIdx.y ? Mtb : Mta;
    int d = blockIdx.x % 7, og = blockIdx.x / 7;
    int o = og * 4 + (threadIdx.x >> 6);
    int ic = threadIdx.x & 63;
    const float* kp = kvT2 + d * 64 + ic;
    const float* wp = wpw + (long)o * 1024;
    float a0 = 0.f, a1 = 0.f, a2 = 0.f, a3 = 0.f;
    for (int c2 = 0; c2 < 1024; c2 += 4) {
        a0 = fmaf(wp[c2],     kp[(long)c2 * 448],       a0);
        a1 = fmaf(wp[c2 + 1], kp[(long)(c2 + 1) * 448], a1);
        a2 = fmaf(wp[c2 + 2], kp[(long)(c2 + 2) * 448], a2);
        a3 = fmaf(wp[c2 + 3], kp[(long)(c2 + 3) * 448], a3);
    }
    Mt[(long)o * 448 + d * 64 + ic] = __float2bfloat16((a0 + a1) + (a2 + a3));
}

// ======================= launch =======================
extern "C" void kernel_launch(void* const* d_in, const int* in_sizes, int n_in,
                              void* d_out, int out_size, void* d_ws, size_t ws_size,
                              hipStream_t stream)
{
    const float* x     = (const float*)d_in[0];
    const float* wq    = (const float*)d_in[1];
    const float* sq    = (const float*)d_in[2];
    const float* bq    = (const float*)d_in[3];
    const float* wk    = (const float*)d_in[4];
    const float* sk    = (const float*)d_in[5];
    const float* bk    = (const float*)d_in[6];
    const float* wv    = (const float*)d_in[7];
    const float* sv    = (const float*)d_in[8];
    const float* bv    = (const float*)d_in[9];
    const float* w_dw  = (const float*)d_in[10];
    const float* s_dw  = (const float*)d_in[11];
    const float* b_dw  = (const float*)d_in[12];
    const float* cov_s = (const float*)d_in[13];
    const float* cov_b = (const float*)d_in[14];
    const float* kv    = (const float*)d_in[15];
    const float* kv3   = (const float*)d_in[16];
    const float* w_pw  = (const float*)d_in[17];
    const float* s_pw  = (const float*)d_in[18];
    const float* b_pw  = (const float*)d_in[19];
    const float* w_row = (const float*)d_in[20];
    const float* s_row = (const float*)d_in[21];
    const float* b_row = (const float*)d_in[22];
    const float* w_col = (const float*)d_in[23];
    const float* s_col = (const float*)d_in[24];
    const float* b_col = (const float*)d_in[25];
    const float* w_proj= (const float*)d_in[26];
    const float* s_proj= (const float*)d_in[27];
    const float* b_proj= (const float*)d_in[28];
    const float* pe_rq = (const float*)d_in[29];
    const float* pe_rk = (const float*)d_in[30];
    const float* pe_cq = (const float*)d_in[31];
    const float* pe_ck = (const float*)d_in[32];
    float* out = (float*)d_out;

    char* wsb = (char*)d_ws;
    size_t off = 0;
    auto alloc = [&](size_t bytes) { char* p = wsb + off; off += (bytes + 255) & ~255UL; return p; };
    bf16*  qkv0   = (bf16*) alloc(67108864);    // (8,1024,4096) bf16
    bf16*  qkvpw  = (bf16*) alloc(16777216);    // (8,256,4096) bf16 raw pre-bn
    bf16*  x_t    = (bf16*) alloc(16777216);    // (8,4096,256) bf16
    bf16*  x1a    = (bf16*) alloc(4194304);     // (8,64,4096) bf16
    bf16*  x3a    = (bf16*) alloc(4194304);
    float* rowm   = (float*)alloc(2097152);     // (8,1024,64)
    float* colm   = (float*)alloc(2097152);
    float* atr    = (float*)alloc(1048576);     // (8,512,64)
    float* atc    = (float*)alloc(1048576);
    float* outr   = (float*)alloc(1048576);
    float* outc   = (float*)alloc(1048576);
    float* Wga    = (float*)alloc(1048576);     // (1024,256)
    float* beta   = (float*)alloc(4096);
    bf16*  Nv_t   = (bf16*) alloc(229376);      // (64,1792)
    bf16*  Nh_t   = (bf16*) alloc(229376);
    float* Cv     = (float*)alloc(1792);
    float* Ch     = (float*)alloc(1792);
    bf16*  Mv_t   = (bf16*) alloc(229376);      // (256,448)
    bf16*  Mh_t   = (bf16*) alloc(229376);
    bf16*  Wall   = (bf16*) alloc(524288);      // (1024,256)
    bf16*  wpw_bf = (bf16*) alloc(524288);      // (256,1024)
    bf16*  wproj_bf = (bf16*)alloc(262144);     // (256,512)
    float* sb_s   = (float*)alloc(4096);
    float* sb_b   = (float*)alloc(4096);
    float* kvT2a  = (float*)alloc(1835008);     // (1024,448)
    float* kvT2b  = (float*)alloc(1835008);
    if (off > ws_size) return;

    const long AB = 512L * 64;

    // ---- weight prep ----
    castw<<<2565, 256, 0, stream>>>(wq, wk, wv, sq, sk, sv, bq, bk, bv, w_pw, w_proj,
                                    Wall, wpw_bf, wproj_bf, sb_s, sb_b);
    cast_xt<<<dim3(64, 4, 8), 256, 0, stream>>>(x, x_t);
    build_wga<<<1024, 256, 0, stream>>>(wq, wk, wv, sq, sk, sv, bq, bk, bv, cov_s, cov_b, Wga, beta);
    build_N<<<dim3(448, 2), 256, 0, stream>>>(kv, kv3, Wga, Nv_t, Nh_t);
    build_C<<<dim3(7, 2), 64, 0, stream>>>(kv, kv3, beta, Cv, Ch);
    kv_transpose<<<dim3(1792, 2), 256, 0, stream>>>(kv, kv3, kvT2a, kvT2b);
    build_M2<<<dim3(448, 2), 256, 0, stream>>>(w_pw, kvT2a, kvT2b, Mv_t, Mh_t);

    // ---- qkv0 = bn(1x1 conv) via MFMA ----
    mfma_qkv<<<dim3(32, 8, 8), 256, 0, stream>>>(x_t, Wall, sb_s, sb_b, qkv0);

    // ---- squeeze attention ----
    meanrc<<<8192, 64, 0, stream>>>(qkv0, rowm, colm);
    attn_kernel<<<dim3(8, 8, 2), 256, 0, stream>>>(rowm, colm, pe_rq, pe_rk, pe_cq, pe_ck, atr, atc);
    gemm1x1<<<dim3(1, 8, 8), 256, 0, stream>>>(atr, AB, 0, w_row, s_row, b_row, outr, AB, 0, 512, 512, 64, 1);
    gemm1x1<<<dim3(1, 8, 8), 256, 0, stream>>>(atc, AB, 0, w_col, s_col, b_col, outc, AB, 0, 512, 512, 64, 1);

    // ---- stripe conv 1 + act_dn ----
    mstripe1<<<dim3(16, 8), 256, 0, stream>>>(x_t, Nv_t, Cv, x1a, 0);
    mstripe1<<<dim3(16, 8), 256, 0, stream>>>(x_t, Nh_t, Ch, x3a, 1);
    softmax_sp_bf<<<1024, 256, 0, stream>>>(x1a, x3a);
    group_renorm_bf<<<2048, 256, 0, stream>>>(x1a, x3a);

    // ---- pw conv with fused dw3x3 (bn deferred) + stripe conv 2 via w_pw ----
    mfma_pw_dw<<<dim3(64, 1, 8), 256, 0, stream>>>(qkv0, wpw_bf, w_dw, s_dw, b_dw, qkvpw);
    mstripe2<<<dim3(32, 2, 8), 256, 0, stream>>>(x1a, x3a, Mv_t, Mh_t, qkvpw);

    // ---- final proj with fused epilogue ----
    mfma_proj<<<dim3(32, 2, 8), 256, 0, stream>>>(qkv0, wproj_bf, outr, outc,
                                                  s_proj, b_proj, qkvpw, s_pw, b_pw, out);
}

// Round 6
// 1102.776 us; speedup vs baseline: 1.0104x; 1.0104x over previous
//
#include <hip/hip_runtime.h>
#include <hip/hip_bf16.h>
#include <math.h>

#define HW 4096
typedef __hip_bfloat16 bf16;
typedef __attribute__((ext_vector_type(8))) short bfrag;
typedef __attribute__((ext_vector_type(4))) float ffrag;

__device__ __forceinline__ float bf2f(short u) {
    return __uint_as_float(((unsigned)(unsigned short)u) << 16);
}
__device__ __forceinline__ short f2bfs(float v) {
    bf16 h = __float2bfloat16(v);
    return *reinterpret_cast<short*>(&h);
}

// ======================= cast + transpose x: [256][4096] -> [4096][256] bf16 ==========
__global__ __launch_bounds__(256) void cast_xt(const float* __restrict__ x, bf16* __restrict__ xt)
{
    __shared__ float t[64][65];
    int b = blockIdx.z, it = blockIdx.y, pt = blockIdx.x;
    int ic0 = it * 64, px0 = pt * 64;
    int tid = threadIdx.x;
    for (int l = 0; l < 16; l++) {
        int e = tid + l * 256;
        int px = e & 63, ic = e >> 6;
        t[ic][px] = x[((long)b * 256 + ic0 + ic) * HW + px0 + px];
    }
    __syncthreads();
    for (int l = 0; l < 16; l++) {
        int e = tid + l * 256;
        int ic = e & 63, px = e >> 6;
        xt[((long)b * HW + px0 + px) * 256 + ic0 + ic] = __float2bfloat16(t[ic][px]);
    }
}

// ======================= weight casts ==========
__global__ __launch_bounds__(256) void castw(
    const float* __restrict__ wq, const float* __restrict__ wk, const float* __restrict__ wv,
    const float* __restrict__ sq, const float* __restrict__ sk, const float* __restrict__ sv,
    const float* __restrict__ bq, const float* __restrict__ bk, const float* __restrict__ bv,
    const float* __restrict__ w_pw, const float* __restrict__ w_proj,
    bf16* __restrict__ Wall, bf16* __restrict__ wpw_bf, bf16* __restrict__ wproj_bf,
    float* __restrict__ sb_s, float* __restrict__ sb_b)
{
    int idx = blockIdx.x * 256 + threadIdx.x;
    if (idx < 262144) {
        int oc = idx >> 8, i = idx & 255;
        float v;
        if (oc < 256) v = wq[oc * 256 + i];
        else if (oc < 512) v = wk[(oc - 256) * 256 + i];
        else v = wv[(oc - 512) * 256 + i];
        Wall[idx] = __float2bfloat16(v);
        return;
    }
    idx -= 262144;
    if (idx < 262144) { wpw_bf[idx] = __float2bfloat16(w_pw[idx]); return; }
    idx -= 262144;
    if (idx < 131072) { wproj_bf[idx] = __float2bfloat16(w_proj[idx]); return; }
    idx -= 131072;
    if (idx < 1024) {
        int oc = idx;
        float s, bb;
        if (oc < 256) { s = sq[oc]; bb = bq[oc]; }
        else if (oc < 512) { s = sk[oc - 256]; bb = bk[oc - 256]; }
        else { s = sv[oc - 512]; bb = bv[oc - 512]; }
        sb_s[oc] = s; sb_b[oc] = bb;
    }
}

// ======================= MFMA qkv GEMM (reg-prefetch pipeline) ==========
__global__ __launch_bounds__(256) void mfma_qkv(
    const bf16* __restrict__ Xt, const bf16* __restrict__ Wall,
    const float* __restrict__ sb_s, const float* __restrict__ sb_b,
    bf16* __restrict__ qkv0)
{
    __shared__ __align__(16) short As[128 * 40];
    __shared__ __align__(16) short Bs[128 * 40];
    int b = blockIdx.z, mt = blockIdx.y, nt = blockIdx.x;
    int oc0 = mt * 128, n0 = nt * 128;
    int tid = threadIdx.x;
    int lane = tid & 63, wave = tid >> 6;
    int lr = lane & 15, quad = lane >> 4;
    int wm = (wave & 1) * 64, wn = (wave >> 1) * 64;
    ffrag acc[4][4];
#pragma unroll
    for (int i = 0; i < 4; i++)
#pragma unroll
        for (int j = 0; j < 4; j++)
#pragma unroll
            for (int r = 0; r < 4; r++) acc[i][j][r] = 0.f;

    int4 apf[2], bpf[2];
#pragma unroll
    for (int l = 0; l < 2; l++) {
        int e = tid + l * 256;
        int r = e >> 2, c = e & 3;
        apf[l] = *(const int4*)&Wall[(long)(oc0 + r) * 256 + c * 8];
        bpf[l] = *(const int4*)&Xt[((long)b * HW + n0 + r) * 256 + c * 8];
    }
    for (int s = 0; s < 8; s++) {
        __syncthreads();
#pragma unroll
        for (int l = 0; l < 2; l++) {
            int e = tid + l * 256;
            int r = e >> 2, c = e & 3;
            *(int4*)&As[r * 40 + c * 8] = apf[l];
            *(int4*)&Bs[r * 40 + c * 8] = bpf[l];
        }
        __syncthreads();
        if (s < 7) {
            int k0 = (s + 1) * 32;
#pragma unroll
            for (int l = 0; l < 2; l++) {
                int e = tid + l * 256;
                int r = e >> 2, c = e & 3;
                apf[l] = *(const int4*)&Wall[(long)(oc0 + r) * 256 + k0 + c * 8];
                bpf[l] = *(const int4*)&Xt[((long)b * HW + n0 + r) * 256 + k0 + c * 8];
            }
        }
        bfrag a[4], bb[4];
#pragma unroll
        for (int i = 0; i < 4; i++) a[i]  = *(const bfrag*)&As[(wm + i * 16 + lr) * 40 + quad * 8];
#pragma unroll
        for (int j = 0; j < 4; j++) bb[j] = *(const bfrag*)&Bs[(wn + j * 16 + lr) * 40 + quad * 8];
#pragma unroll
        for (int i = 0; i < 4; i++)
#pragma unroll
            for (int j = 0; j < 4; j++)
                acc[i][j] = __builtin_amdgcn_mfma_f32_16x16x32_bf16(a[i], bb[j], acc[i][j], 0, 0, 0);
    }
#pragma unroll
    for (int i = 0; i < 4; i++)
#pragma unroll
        for (int r = 0; r < 4; r++) {
            int row = oc0 + wm + i * 16 + quad * 4 + r;
            float s = sb_s[row], bb2 = sb_b[row];
#pragma unroll
            for (int j = 0; j < 4; j++) {
                int col = n0 + wn + j * 16 + lr;
                qkv0[((long)b * 1024 + row) * HW + col] = __float2bfloat16(fmaf(s, acc[i][j][r], bb2));
            }
        }
}

// ======================= MFMA pw GEMM, M=256 tile, fused dw3x3, XOR-swizzled B ==========
// grid (64 y, 1, 8 b); qkvpw[b][256][4096] bf16 (raw pre-bn)
// B LDS row = sigma(px) = (px&7)*8 + ((px>>3)^(px&7)); stride 40 shorts.
__global__ __launch_bounds__(256, 2) void mfma_pw_dw(
    const bf16* __restrict__ qkv0, const bf16* __restrict__ wpw_bf,
    const float* __restrict__ w_dw, const float* __restrict__ s_dw, const float* __restrict__ b_dw,
    bf16* __restrict__ qkvpw)
{
    __shared__ __align__(16) short As[256 * 40];   // 20 KB
    __shared__ __align__(16) short Bst[64 * 40];   // 5 KB
    int b = blockIdx.z, y = blockIdx.x;
    int px0 = y * 64;
    int tid = threadIdx.x;
    int lane = tid & 63, wave = tid >> 6;
    int lr = lane & 15, quad = lane >> 4;
    int wm = wave * 64;
    int dc = tid >> 3;          // 0..31: k within slab
    int ux = tid & 7;           // 0..7:  px group of 8
    int xb = ux * 8;
    ffrag acc[4][4];
#pragma unroll
    for (int i = 0; i < 4; i++)
#pragma unroll
        for (int j = 0; j < 4; j++)
#pragma unroll
            for (int r = 0; r < 4; r++) acc[i][j][r] = 0.f;

    int4 apf[4];
    int4 midpf[3]; short lopf[3], hipf[3];
    float wdpf[9], sspf, bbpf;
    {
        int k0 = 0;
#pragma unroll
        for (int l = 0; l < 4; l++) {
            int e = tid + l * 256;
            int r = e >> 2, c = e & 3;
            apf[l] = *(const int4*)&wpw_bf[(long)r * 1024 + k0 + c * 8];
        }
        int ch = k0 + dc;
        const bf16* base = qkv0 + ((long)b * 1024 + ch) * HW;
#pragma unroll
        for (int dy = 0; dy < 3; dy++) {
            int gr = y + dy - 1;
            bool vr = (gr >= 0 && gr < 64);
            int4 z = {0,0,0,0};
            midpf[dy] = vr ? *(const int4*)&base[gr * 64 + xb] : z;
            lopf[dy] = (vr && ux > 0) ? *(const short*)&base[gr * 64 + xb - 1] : (short)0;
            hipf[dy] = (vr && ux < 7) ? *(const short*)&base[gr * 64 + xb + 8] : (short)0;
        }
#pragma unroll
        for (int t = 0; t < 9; t++) wdpf[t] = w_dw[ch * 9 + t];
        sspf = s_dw[ch]; bbpf = b_dw[ch];
    }

    for (int s = 0; s < 32; s++) {
        short pk[8];
        {
            float o8[8];
#pragma unroll
            for (int o = 0; o < 8; o++) o8[o] = 0.f;
#pragma unroll
            for (int dy = 0; dy < 3; dy++) {
                float w10[10];
                short m8[8];
                *(int4*)m8 = midpf[dy];
                w10[0] = bf2f(lopf[dy]);
#pragma unroll
                for (int t = 0; t < 8; t++) w10[t + 1] = bf2f(m8[t]);
                w10[9] = bf2f(hipf[dy]);
#pragma unroll
                for (int dx = 0; dx < 3; dx++) {
                    float wt = wdpf[dy * 3 + dx];
#pragma unroll
                    for (int o = 0; o < 8; o++)
                        o8[o] = fmaf(wt, w10[o + dx], o8[o]);
                }
            }
#pragma unroll
            for (int o = 0; o < 8; o++)
                pk[o] = f2bfs(fmaxf(fmaf(sspf, o8[o], bbpf), 0.f));
        }
        __syncthreads();
#pragma unroll
        for (int l = 0; l < 4; l++) {
            int e = tid + l * 256;
            int r = e >> 2, c = e & 3;
            *(int4*)&As[r * 40 + c * 8] = apf[l];
        }
#pragma unroll
        for (int o = 0; o < 8; o++)
            Bst[(o * 8 + (ux ^ o)) * 40 + dc] = pk[o];   // sigma(px=ux*8+o)
        __syncthreads();
        if (s < 31) {
            int k0 = (s + 1) * 32;
#pragma unroll
            for (int l = 0; l < 4; l++) {
                int e = tid + l * 256;
                int r = e >> 2, c = e & 3;
                apf[l] = *(const int4*)&wpw_bf[(long)r * 1024 + k0 + c * 8];
            }
            int ch = k0 + dc;
            const bf16* base = qkv0 + ((long)b * 1024 + ch) * HW;
#pragma unroll
            for (int dy = 0; dy < 3; dy++) {
                int gr = y + dy - 1;
                bool vr = (gr >= 0 && gr < 64);
                int4 z = {0,0,0,0};
                midpf[dy] = vr ? *(const int4*)&base[gr * 64 + xb] : z;
                lopf[dy] = (vr && ux > 0) ? *(const short*)&base[gr * 64 + xb - 1] : (short)0;
                hipf[dy] = (vr && ux < 7) ? *(const short*)&base[gr * 64 + xb + 8] : (short)0;
            }
#pragma unroll
            for (int t = 0; t < 9; t++) wdpf[t] = w_dw[ch * 9 + t];
            sspf = s_dw[ch]; bbpf = b_dw[ch];
        }
        bfrag a[4], bb[4];
#pragma unroll
        for (int i = 0; i < 4; i++) a[i] = *(const bfrag*)&As[(wm + i * 16 + lr) * 40 + quad * 8];
#pragma unroll
        for (int j = 0; j < 4; j++) {
            int brow = (lr & 7) * 8 + ((j * 2 + (lr >> 3)) ^ (lr & 7));   // sigma(px=j*16+lr)
            bb[j] = *(const bfrag*)&Bst[brow * 40 + quad * 8];
        }
#pragma unroll
        for (int i = 0; i < 4; i++)
#pragma unroll
            for (int j = 0; j < 4; j++)
                acc[i][j] = __builtin_amdgcn_mfma_f32_16x16x32_bf16(a[i], bb[j], acc[i][j], 0, 0, 0);
    }
#pragma unroll
    for (int i = 0; i < 4; i++)
#pragma unroll
        for (int r = 0; r < 4; r++) {
            int row = wm + i * 16 + quad * 4 + r;
#pragma unroll
            for (int j = 0; j < 4; j++) {
                int col = px0 + j * 16 + lr;
                qkvpw[((long)b * 256 + row) * HW + col] = __float2bfloat16(acc[i][j][r]);
            }
        }
}

// ======================= MFMA proj GEMM with fused epilogue, XOR-swizzled B ==========
// B LDS row = sigma7(px) = (px&7)*16 + ((px>>3)^(px&7)); stride 40 shorts.
__global__ __launch_bounds__(256, 2) void mfma_proj(
    const bf16* __restrict__ qkv0, const bf16* __restrict__ wproj_bf,
    const float* __restrict__ outr, const float* __restrict__ outc,
    const float* __restrict__ s_proj, const float* __restrict__ b_proj,
    const bf16* __restrict__ qkvpw, const float* __restrict__ s_pw, const float* __restrict__ b_pw,
    float* __restrict__ out)
{
    __shared__ __align__(16) short As[128 * 40];
    __shared__ __align__(16) short Bst[128 * 40];
    int b = blockIdx.z, mt = blockIdx.y, nt = blockIdx.x;
    int oc0 = mt * 128, y0 = nt * 2, px0 = nt * 128;
    int tid = threadIdx.x;
    int lane = tid & 63, wave = tid >> 6;
    int lr = lane & 15, quad = lane >> 4;
    int wm = (wave & 1) * 64, wn = (wave >> 1) * 64;
    ffrag acc[4][4];
#pragma unroll
    for (int i = 0; i < 4; i++)
#pragma unroll
        for (int j = 0; j < 4; j++)
#pragma unroll
            for (int r = 0; r < 4; r++) acc[i][j][r] = 0.f;

    int4 apf[2], vpf[2];
    float ropf[2]; float4 ocpf[2][2];
#pragma unroll
    for (int l = 0; l < 2; l++) {
        int e = tid + l * 256;
        int r = e >> 2, c4 = e & 3;
        apf[l] = *(const int4*)&wproj_bf[(long)(oc0 + r) * 512 + c4 * 8];
        int cx = e & 15, c = e >> 4;
        vpf[l] = *(const int4*)&qkv0[((long)b * 1024 + 512 + c) * HW + px0 + cx * 8];
        ropf[l] = outr[((long)b * 512 + c) * 64 + y0 + (cx >> 3)];
        const float* cbase = &outc[((long)b * 512 + c) * 64 + (cx & 7) * 8];
        ocpf[l][0] = *(const float4*)&cbase[0];
        ocpf[l][1] = *(const float4*)&cbase[4];
    }
    for (int s = 0; s < 16; s++) {
        __syncthreads();
#pragma unroll
        for (int l = 0; l < 2; l++) {
            int e = tid + l * 256;
            int r = e >> 2, c4 = e & 3;
            *(int4*)&As[r * 40 + c4 * 8] = apf[l];
            int cx = e & 15, c = e >> 4;
            short v8[8];
            *(int4*)v8 = vpf[l];
            float oc8[8];
            *(float4*)&oc8[0] = ocpf[l][0];
            *(float4*)&oc8[4] = ocpf[l][1];
#pragma unroll
            for (int p = 0; p < 8; p++) {
                float val = bf2f(v8[p]) + ropf[l] + oc8[p];
                Bst[(p * 16 + (cx ^ p)) * 40 + c] = f2bfs(fmaxf(val, 0.f));  // sigma7(px=cx*8+p)
            }
        }
        __syncthreads();
        if (s < 15) {
            int k0 = (s + 1) * 32;
#pragma unroll
            for (int l = 0; l < 2; l++) {
                int e = tid + l * 256;
                int r = e >> 2, c4 = e & 3;
                apf[l] = *(const int4*)&wproj_bf[(long)(oc0 + r) * 512 + k0 + c4 * 8];
                int cx = e & 15, c = e >> 4;
                int dh = k0 + c;
                vpf[l] = *(const int4*)&qkv0[((long)b * 1024 + 512 + dh) * HW + px0 + cx * 8];
                ropf[l] = outr[((long)b * 512 + dh) * 64 + y0 + (cx >> 3)];
                const float* cbase = &outc[((long)b * 512 + dh) * 64 + (cx & 7) * 8];
                ocpf[l][0] = *(const float4*)&cbase[0];
                ocpf[l][1] = *(const float4*)&cbase[4];
            }
        }
        bfrag a[4], bb[4];
#pragma unroll
        for (int i = 0; i < 4; i++) a[i] = *(const bfrag*)&As[(wm + i * 16 + lr) * 40 + quad * 8];
#pragma unroll
        for (int j = 0; j < 4; j++) {
            int bidx = (wn >> 3) + j * 2 + (lr >> 3);
            int brow = (lr & 7) * 16 + (bidx ^ (lr & 7));   // sigma7(px=wn+j*16+lr)
            bb[j] = *(const bfrag*)&Bst[brow * 40 + quad * 8];
        }
#pragma unroll
        for (int i = 0; i < 4; i++)
#pragma unroll
            for (int j = 0; j < 4; j++)
                acc[i][j] = __builtin_amdgcn_mfma_f32_16x16x32_bf16(a[i], bb[j], acc[i][j], 0, 0, 0);
    }
#pragma unroll
    for (int i = 0; i < 4; i++)
#pragma unroll
        for (int r = 0; r < 4; r++) {
            int row = oc0 + wm + i * 16 + quad * 4 + r;
            float sp = s_proj[row], bp = b_proj[row];
            float sw = s_pw[row], bw = b_pw[row];
#pragma unroll
            for (int j = 0; j < 4; j++) {
                int col = px0 + wn + j * 16 + lr;
                long idx = ((long)b * 256 + row) * HW + col;
                float t = fmaf(sp, acc[i][j][r], bp);
                float m = fmaf(sw, bf2f(*(const short*)&qkvpw[idx]), bw);
                out[idx] = m / (1.f + __expf(-t));
            }
        }
}

// ======================= MFMA stripe conv 1 (A-prefetch) ==========
__global__ __launch_bounds__(256) void mstripe1(
    const bf16* __restrict__ xt, const bf16* __restrict__ Nt, const float* __restrict__ C,
    bf16* __restrict__ outp, int dir)
{
    __shared__ __align__(16) short As[64 * 264];
    int b = blockIdx.y;
    int tid = threadIdx.x;
    int wave = tid >> 6, lane = tid & 63;
    int lr = lane & 15, quad = lane >> 4;
    int y = blockIdx.x * 4 + wave;
    ffrag acc[4][4];
#pragma unroll
    for (int i = 0; i < 4; i++)
#pragma unroll
        for (int j = 0; j < 4; j++)
#pragma unroll
            for (int r = 0; r < 4; r++) acc[i][j][r] = 0.f;
    bfrag zf;
#pragma unroll
    for (int e = 0; e < 8; e++) zf[e] = 0;

    int4 apf[8];
#pragma unroll
    for (int l = 0; l < 8; l++) {
        int e = tid + l * 256;
        int oc = e >> 5, c = e & 31;
        apf[l] = *(const int4*)&Nt[(long)oc * 1792 + c * 8];
    }
    for (int d = 0; d < 7; d++) {
        __syncthreads();
#pragma unroll
        for (int l = 0; l < 8; l++) {
            int e = tid + l * 256;
            int oc = e >> 5, c = e & 31;
            *(int4*)&As[oc * 264 + c * 8] = apf[l];
        }
        __syncthreads();
        if (d < 6) {
#pragma unroll
            for (int l = 0; l < 8; l++) {
                int e = tid + l * 256;
                int oc = e >> 5, c = e & 31;
                apf[l] = *(const int4*)&Nt[(long)oc * 1792 + (d + 1) * 256 + c * 8];
            }
        }
        int off = d - 3;
        int row = y + off;
        bool vrow = (row >= 0 && row < 64);
        for (int ks = 0; ks < 8; ks++) {
            bfrag a[4], bb[4];
#pragma unroll
            for (int i = 0; i < 4; i++)
                a[i] = *(const bfrag*)&As[(i * 16 + lr) * 264 + ks * 32 + quad * 8];
#pragma unroll
            for (int j = 0; j < 4; j++) {
                int x = j * 16 + lr;
                if (dir == 0) {
                    bb[j] = vrow ? *(const bfrag*)&xt[((long)b * HW + row * 64 + x) * 256 + ks * 32 + quad * 8] : zf;
                } else {
                    int xs = x + off;
                    bb[j] = (xs >= 0 && xs < 64)
                        ? *(const bfrag*)&xt[((long)b * HW + y * 64 + xs) * 256 + ks * 32 + quad * 8] : zf;
                }
            }
#pragma unroll
            for (int i = 0; i < 4; i++)
#pragma unroll
                for (int j = 0; j < 4; j++)
                    acc[i][j] = __builtin_amdgcn_mfma_f32_16x16x32_bf16(a[i], bb[j], acc[i][j], 0, 0, 0);
        }
    }
#pragma unroll
    for (int i = 0; i < 4; i++)
#pragma unroll
        for (int r = 0; r < 4; r++) {
            int oc = i * 16 + quad * 4 + r;
#pragma unroll
            for (int j = 0; j < 4; j++) {
                int x = j * 16 + lr;
                float ct = 0.f;
                int base = dir ? x : y;
                for (int d = 0; d < 7; d++) {
                    int t = base + d - 3;
                    if (t >= 0 && t < 64) ct += C[d * 64 + oc];
                }
                outp[((long)b * 64 + oc) * HW + y * 64 + x] = __float2bfloat16(acc[i][j][r] + ct);
            }
        }
}

// ======================= MFMA stripe conv 2, both dirs, XOR-swizzled B ==========
__device__ __forceinline__ void ms2_load(
    int t, int b, int y0, int oc0, int tid,
    const bf16* __restrict__ x1a, const bf16* __restrict__ x3a,
    const bf16* __restrict__ Mv, const bf16* __restrict__ Mh,
    int4* apf, short bpf[2][8])
{
    int dir = t / 14, rem = t - dir * 14, d = rem >> 1, ks = rem & 1;
    const bf16* inp = dir ? x3a : x1a;
    const bf16* Mt  = dir ? Mh  : Mv;
    int off = d - 3;
#pragma unroll
    for (int l = 0; l < 2; l++) {
        int e = tid + l * 256;
        int r = e >> 2, c4 = e & 3;
        apf[l] = *(const int4*)&Mt[(long)(oc0 + r) * 448 + d * 64 + ks * 32 + c4 * 8];
        int cx = e & 15, c = e >> 4;
        int ic = ks * 32 + c;
        const bf16* src = &inp[((long)b * 64 + ic) * HW];
        if (dir == 0) {
            int srow = y0 + (cx >> 3) + off;
            if (srow >= 0 && srow < 64)
                *(int4*)bpf[l] = *(const int4*)&src[srow * 64 + (cx & 7) * 8];
            else {
                int4 z = {0,0,0,0};
                *(int4*)bpf[l] = z;
            }
        } else {
            int row = y0 + (cx >> 3);
#pragma unroll
            for (int p = 0; p < 8; p++) {
                int xs = (cx & 7) * 8 + p + off;
                bpf[l][p] = (xs >= 0 && xs < 64) ? *(const short*)&src[row * 64 + xs] : (short)0;
            }
        }
    }
}

__global__ __launch_bounds__(256, 2) void mstripe2(
    const bf16* __restrict__ x1a, const bf16* __restrict__ x3a,
    const bf16* __restrict__ Mv, const bf16* __restrict__ Mh,
    bf16* __restrict__ qkvpw)
{
    __shared__ __align__(16) short As[128 * 40];
    __shared__ __align__(16) short Bst[128 * 40];
    int b = blockIdx.z, mt = blockIdx.y, nt = blockIdx.x;
    int oc0 = mt * 128, y0 = nt * 2, px0 = nt * 128;
    int tid = threadIdx.x;
    int lane = tid & 63, wave = tid >> 6;
    int lr = lane & 15, quad = lane >> 4;
    int wm = (wave & 1) * 64, wn = (wave >> 1) * 64;
    ffrag acc[4][4];
#pragma unroll
    for (int i = 0; i < 4; i++)
#pragma unroll
        for (int j = 0; j < 4; j++)
#pragma unroll
            for (int r = 0; r < 4; r++) acc[i][j][r] = 0.f;

    int4 apf[2]; short bpf[2][8];
    ms2_load(0, b, y0, oc0, tid, x1a, x3a, Mv, Mh, apf, bpf);
    for (int t = 0; t < 28; t++) {
        __syncthreads();
#pragma unroll
        for (int l = 0; l < 2; l++) {
            int e = tid + l * 256;
            int r = e >> 2, c4 = e & 3;
            *(int4*)&As[r * 40 + c4 * 8] = apf[l];
            int cx = e & 15, c = e >> 4;
#pragma unroll
            for (int p = 0; p < 8; p++)
                Bst[(p * 16 + (cx ^ p)) * 40 + c] = bpf[l][p];   // sigma7
        }
        __syncthreads();
        if (t < 27)
            ms2_load(t + 1, b, y0, oc0, tid, x1a, x3a, Mv, Mh, apf, bpf);
        bfrag a[4], bb[4];
#pragma unroll
        for (int i = 0; i < 4; i++) a[i] = *(const bfrag*)&As[(wm + i * 16 + lr) * 40 + quad * 8];
#pragma unroll
        for (int j = 0; j < 4; j++) {
            int bidx = (wn >> 3) + j * 2 + (lr >> 3);
            int brow = (lr & 7) * 16 + (bidx ^ (lr & 7));
            bb[j] = *(const bfrag*)&Bst[brow * 40 + quad * 8];
        }
#pragma unroll
        for (int i = 0; i < 4; i++)
#pragma unroll
            for (int j = 0; j < 4; j++)
                acc[i][j] = __builtin_amdgcn_mfma_f32_16x16x32_bf16(a[i], bb[j], acc[i][j], 0, 0, 0);
    }
#pragma unroll
    for (int i = 0; i < 4; i++)
#pragma unroll
        for (int r = 0; r < 4; r++) {
            int row = oc0 + wm + i * 16 + quad * 4 + r;
#pragma unroll
            for (int j = 0; j < 4; j++) {
                int col = px0 + wn + j * 16 + lr;
                long idx = ((long)b * 256 + row) * HW + col;
                float v = bf2f(*(const short*)&qkvpw[idx]) + acc[i][j][r];
                qkvpw[idx] = __float2bfloat16(v);
            }
        }
}

// ======================= act_dn (bf16, register-resident, both tensors) ==========
__global__ __launch_bounds__(256) void softmax_sp_bf(bf16* __restrict__ x1, bf16* __restrict__ x3)
{
    __shared__ float red[4];
    int bc = blockIdx.x;   // 0..1023
    bf16* p = (bc < 512) ? (x1 + (long)bc * HW) : (x3 + (long)(bc - 512) * HW);
    int tid = threadIdx.x;
    float v[16];
#pragma unroll
    for (int i = 0; i < 16; i++) v[i] = __bfloat162float(p[tid + i * 256]);
    float m = -1e30f;
#pragma unroll
    for (int i = 0; i < 16; i++) m = fmaxf(m, v[i]);
    for (int o = 32; o > 0; o >>= 1) m = fmaxf(m, __shfl_down(m, o));
    if ((tid & 63) == 0) red[tid >> 6] = m;
    __syncthreads();
    m = fmaxf(fmaxf(red[0], red[1]), fmaxf(red[2], red[3]));
    __syncthreads();
    float z = 0.f;
#pragma unroll
    for (int i = 0; i < 16; i++) { v[i] = __expf(v[i] - m); z += v[i]; }
    for (int o = 32; o > 0; o >>= 1) z += __shfl_down(z, o);
    if ((tid & 63) == 0) red[tid >> 6] = z;
    __syncthreads();
    z = red[0] + red[1] + red[2] + red[3];
    float inv = 1.f / z;
#pragma unroll
    for (int i = 0; i < 16; i++) p[tid + i * 256] = __float2bfloat16(v[i] * inv);
}

__global__ __launch_bounds__(256) void group_renorm_bf(bf16* __restrict__ x1, bf16* __restrict__ x3)
{
    int which = blockIdx.x >> 10;
    long t = (long)(blockIdx.x & 1023) * 256 + threadIdx.x;   // B*8*4096
    bf16* x = which ? x3 : x1;
    int s = (int)(t & 4095);
    int h = (int)((t >> 12) & 7);
    int b = (int)(t >> 15);
    bf16* base = x + (((long)(b * 64 + h * 8)) << 12) + s;
    float v[8]; float g = 0.f;
#pragma unroll
    for (int j = 0; j < 8; j++) { v[j] = __bfloat162float(base[(long)j << 12]); g += v[j]; }
    float inv = 1.f / (g + 1e-6f);
#pragma unroll
    for (int j = 0; j < 8; j++) base[(long)j << 12] = __float2bfloat16(v[j] * inv);
}

// ======================= row/col means of qkv0 (bf16) =======================
__global__ __launch_bounds__(64) void meanrc(
    const bf16* __restrict__ in, float* __restrict__ rowm, float* __restrict__ colm)
{
    __shared__ float tile[64][65];
    int bc = blockIdx.x;
    const bf16* p = in + (long)bc * HW;
    int t = threadIdx.x;
    for (int i = 0; i < 64; i++) tile[i][t] = __bfloat162float(p[i * 64 + t]);
    __syncthreads();
    float rs = 0.f, cs = 0.f;
    for (int i = 0; i < 64; i++) { rs += tile[t][i]; cs += tile[i][t]; }
    rowm[(long)bc * 64 + t] = rs * (1.f / 64.f);
    colm[(long)bc * 64 + t] = cs * (1.f / 64.f);
}

// ======================= squeeze attention =======================
__device__ __forceinline__ float interp_pe(const float* pe, int c, int i)
{
    float coord = fminf(fmaxf((i + 0.5f) * 0.25f - 0.5f, 0.f), 15.f);
    int lo = (int)coord;
    int hi = min(lo + 1, 15);
    float t = coord - (float)lo;
    return pe[c * 16 + lo] * (1.f - t) + pe[c * 16 + hi] * t;
}

__global__ __launch_bounds__(256) void attn_kernel(
    const float* __restrict__ rowm, const float* __restrict__ colm,
    const float* __restrict__ pe_rq, const float* __restrict__ pe_rk,
    const float* __restrict__ pe_cq, const float* __restrict__ pe_ck,
    float* __restrict__ outr, float* __restrict__ outc)
{
    int h = blockIdx.x, b = blockIdx.y, dir = blockIdx.z;
    const float* mean = dir ? colm : rowm;
    const float* peq = dir ? pe_cq : pe_rq;
    const float* pek = dir ? pe_ck : pe_rk;
    float* outp = (dir ? outc : outr) + ((long)b * 512 + h * 64) * 64;
    __shared__ float qs[32][64], ks[32][64], vs[64][64], S[64][66];
    int tid = threadIdx.x;

    for (int e = tid; e < 2048; e += 256) {
        int c = e >> 6, i = e & 63;
        int gc = h * 32 + c;
        qs[c][i] = mean[((long)b * 1024 + gc) * 64 + i]       + interp_pe(peq, gc, i);
        ks[c][i] = mean[((long)b * 1024 + 256 + gc) * 64 + i] + interp_pe(pek, gc, i);
    }
    for (int e = tid; e < 4096; e += 256) {
        int dc = e >> 6, j = e & 63;
        vs[dc][j] = mean[((long)b * 1024 + 512 + h * 64 + dc) * 64 + j];
    }
    __syncthreads();
    const float scl = 0.17677669529663687f;
    for (int e = tid; e < 4096; e += 256) {
        int i = e >> 6, j = e & 63;
        float s = 0.f;
#pragma unroll
        for (int c = 0; c < 32; c++) s = fmaf(qs[c][i], ks[c][j], s);
        S[i][j] = s * scl;
    }
    __syncthreads();
    if (tid < 64) {
        int i = tid;
        float m = -1e30f;
        for (int j = 0; j < 64; j++) m = fmaxf(m, S[i][j]);
        float z = 0.f;
        for (int j = 0; j < 64; j++) { float e2 = __expf(S[i][j] - m); S[i][j] = e2; z += e2; }
        float inv = 1.f / z;
        for (int j = 0; j < 64; j++) S[i][j] *= inv;
    }
    __syncthreads();
    for (int e = tid; e < 4096; e += 256) {
        int dc = e >> 6, i = e & 63;
        float o = 0.f;
#pragma unroll
        for (int j = 0; j < 64; j++) o = fmaf(S[i][j], vs[dc][j], o);
        outp[dc * 64 + i] = o;
    }
}

// ======================= small fp32 GEMM (row/col attention projections) ==========
__global__ __launch_bounds__(256) void gemm1x1(
    const void* __restrict__ X, long x_b, int in_bf16,
    const float* __restrict__ W,
    const float* __restrict__ scale, const float* __restrict__ bias,
    void* __restrict__ out, long o_b, int out_bf16,
    int OC, int IC, int NP,
    int relu_in)
{
    __shared__ __align__(16) float As[16][68];
    __shared__ __align__(16) float Bs[16][64];
    int b  = blockIdx.z;
    int oc0 = blockIdx.y * 64;
    int n0  = blockIdx.x * 64;
    int tid = threadIdx.x;
    int tx = tid & 15, ty = tid >> 4;
    float acc[4][4] = {};

    for (int k0 = 0; k0 < IC; k0 += 16) {
#pragma unroll
        for (int l = 0; l < 4; l++) {
            int e = tid + l * 256;
            int oc = e >> 4, kk = e & 15;
            As[kk][oc] = W[(long)(oc0 + oc) * IC + (k0 + kk)];
        }
#pragma unroll
        for (int l = 0; l < 4; l++) {
            int e = tid + l * 256;
            int kk = e >> 6, n = e & 63;
            int ic = k0 + kk;
            long xi = (long)b * x_b + (long)ic * NP + (n0 + n);
            float v = in_bf16 ? __bfloat162float(((const bf16*)X)[xi])
                              : ((const float*)X)[xi];
            if (relu_in) v = fmaxf(v, 0.f);
            Bs[kk][n] = v;
        }
        __syncthreads();
#pragma unroll
        for (int kk = 0; kk < 16; kk++) {
            float a[4], bv[4];
            *(float4*)a  = *(const float4*)&As[kk][ty * 4];
            *(float4*)bv = *(const float4*)&Bs[kk][tx * 4];
#pragma unroll
            for (int i = 0; i < 4; i++)
#pragma unroll
                for (int j = 0; j < 4; j++)
                    acc[i][j] = fmaf(a[i], bv[j], acc[i][j]);
        }
        __syncthreads();
    }

#pragma unroll
    for (int i = 0; i < 4; i++) {
        int oc = oc0 + ty * 4 + i;
        float s  = scale ? scale[oc] : 1.f;
        float bb = bias  ? bias[oc]  : 0.f;
#pragma unroll
        for (int j = 0; j < 4; j++) {
            int n = n0 + tx * 4 + j;
            float v = fmaf(s, acc[i][j], bb);
            long oidx = (long)b * o_b + (long)oc * NP + n;
            if (out_bf16) ((bf16*)out)[oidx] = __float2bfloat16(v);
            else          ((float*)out)[oidx] = v;
        }
    }
}

// ======================= weight pre-contraction =======================
__global__ __launch_bounds__(256) void build_wga(
    const float* __restrict__ wq, const float* __restrict__ wk, const float* __restrict__ wv,
    const float* __restrict__ sq, const float* __restrict__ sk, const float* __restrict__ sv,
    const float* __restrict__ bq, const float* __restrict__ bk, const float* __restrict__ bv,
    const float* __restrict__ cov_s, const float* __restrict__ cov_b,
    float* __restrict__ Wga, float* __restrict__ beta)
{
    int idx = blockIdx.x * 256 + threadIdx.x;
    int ic = idx >> 8, i = idx & 255;
    const float* Wp; float sth, bth;
    if (ic < 256)      { Wp = wq + ic * 256;         sth = sq[ic];       bth = bq[ic]; }
    else if (ic < 512) { Wp = wk + (ic - 256) * 256; sth = sk[ic - 256]; bth = bk[ic - 256]; }
    else               { Wp = wv + (ic - 512) * 256; sth = sv[ic - 512]; bth = bv[ic - 512]; }
    Wga[idx] = cov_s[ic] * sth * Wp[i];
    if (i == 0) beta[ic] = cov_s[ic] * bth + cov_b[ic];
}

// N_t[oc][d*256 + i] = sum_ic kv[oc, ic, d] * Wga[ic, i] ; grid (448, 2)
__global__ __launch_bounds__(256) void build_N(
    const float* __restrict__ kva, const float* __restrict__ kvb,
    const float* __restrict__ Wga, bf16* __restrict__ Nta, bf16* __restrict__ Ntb)
{
    const float* kvw = blockIdx.y ? kvb : kva;
    bf16* Nt = blockIdx.y ? Ntb : Nta;
    int d = blockIdx.x >> 6, oc = blockIdx.x & 63;
    int i = threadIdx.x;
    float a0 = 0.f, a1 = 0.f, a2 = 0.f, a3 = 0.f;
    for (int ic = 0; ic < 1024; ic += 4) {
        a0 = fmaf(kvw[oc * 7168 + ic * 7 + d],           Wga[ic * 256 + i],           a0);
        a1 = fmaf(kvw[oc * 7168 + (ic + 1) * 7 + d],     Wga[(ic + 1) * 256 + i],     a1);
        a2 = fmaf(kvw[oc * 7168 + (ic + 2) * 7 + d],     Wga[(ic + 2) * 256 + i],     a2);
        a3 = fmaf(kvw[oc * 7168 + (ic + 3) * 7 + d],     Wga[(ic + 3) * 256 + i],     a3);
    }
    Nt[(long)oc * 1792 + d * 256 + i] = __float2bfloat16((a0 + a1) + (a2 + a3));
}

// grid (7, 2)
__global__ __launch_bounds__(64) void build_C(
    const float* __restrict__ kva, const float* __restrict__ kvb,
    const float* __restrict__ beta, float* __restrict__ Ca, float* __restrict__ Cb)
{
    const float* kvw = blockIdx.y ? kvb : kva;
    float* C = blockIdx.y ? Cb : Ca;
    int d = blockIdx.x, oc = threadIdx.x;
    float a = 0.f;
    for (int ic = 0; ic < 1024; ic++)
        a = fmaf(kvw[oc * 7168 + ic * 7 + d], beta[ic], a);
    C[d * 64 + oc] = a;
}

// kvT2[c2][d*64+ic] = kv[ic][c2][d] ; grid (1792, 2)
__global__ __launch_bounds__(256) void kv_transpose(
    const float* __restrict__ kva, const float* __restrict__ kvb,
    float* __restrict__ kvT2a, float* __restrict__ kvT2b)
{
    const float* kvw = blockIdx.y ? kvb : kva;
    float* kvT2 = blockIdx.y ? kvT2b : kvT2a;
    int idx = blockIdx.x * 256 + threadIdx.x;
    if (idx >= 458752) return;
    int c2 = idx / 448;
    int rem = idx - c2 * 448;
    int d = rem >> 6, ic = rem & 63;
    kvT2[idx] = kvw[ic * 7168 + c2 * 7 + d];
}

// M_t[o][d*64 + ic] = sum_c2 wpw[o][c2] * kvT2[c2][d*64+ic] ; grid (448, 2)
__global__ __launch_bounds__(256) void build_M2(
    const float* __restrict__ wpw,
    const float* __restrict__ kvT2a, const float* __restrict__ kvT2b,
    bf16* __restrict__ Mta, bf16* __restrict__ Mtb)
{
    const float* kvT2 = blockIdx.y ? kvT2b : kvT2a;
    bf16* Mt = blockIdx.y ? Mtb : Mta;
    int d = blockIdx.x % 7, og = blockIdx.x / 7;
    int o = og * 4 + (threadIdx.x >> 6);
    int ic = threadIdx.x & 63;
    const float* kp = kvT2 + d * 64 + ic;
    const float* wp = wpw + (long)o * 1024;
    float a0 = 0.f, a1 = 0.f, a2 = 0.f, a3 = 0.f;
    for (int c2 = 0; c2 < 1024; c2 += 4) {
        a0 = fmaf(wp[c2],     kp[(long)c2 * 448],       a0);
        a1 = fmaf(wp[c2 + 1], kp[(long)(c2 + 1) * 448], a1);
        a2 = fmaf(wp[c2 + 2], kp[(long)(c2 + 2) * 448], a2);
        a3 = fmaf(wp[c2 + 3], kp[(long)(c2 + 3) * 448], a3);
    }
    Mt[(long)o * 448 + d * 64 + ic] = __float2bfloat16((a0 + a1) + (a2 + a3));
}

// ======================= launch =======================
extern "C" void kernel_launch(void* const* d_in, const int* in_sizes, int n_in,
                              void* d_out, int out_size, void* d_ws, size_t ws_size,
                              hipStream_t stream)
{
    const float* x     = (const float*)d_in[0];
    const float* wq    = (const float*)d_in[1];
    const float* sq    = (const float*)d_in[2];
    const float* bq    = (const float*)d_in[3];
    const float* wk    = (const float*)d_in[4];
    const float* sk    = (const float*)d_in[5];
    const float* bk    = (const float*)d_in[6];
    const float* wv    = (const float*)d_in[7];
    const float* sv    = (const float*)d_in[8];
    const float* bv    = (const float*)d_in[9];
    const float* w_dw  = (const float*)d_in[10];
    const float* s_dw  = (const float*)d_in[11];
    const float* b_dw  = (const float*)d_in[12];
    const float* cov_s = (const float*)d_in[13];
    const float* cov_b = (const float*)d_in[14];
    const float* kv    = (const float*)d_in[15];
    const float* kv3   = (const float*)d_in[16];
    const float* w_pw  = (const float*)d_in[17];
    const float* s_pw  = (const float*)d_in[18];
    const float* b_pw  = (const float*)d_in[19];
    const float* w_row = (const float*)d_in[20];
    const float* s_row = (const float*)d_in[21];
    const float* b_row = (const float*)d_in[22];
    const float* w_col = (const float*)d_in[23];
    const float* s_col = (const float*)d_in[24];
    const float* b_col = (const float*)d_in[25];
    const float* w_proj= (const float*)d_in[26];
    const float* s_proj= (const float*)d_in[27];
    const float* b_proj= (const float*)d_in[28];
    const float* pe_rq = (const float*)d_in[29];
    const float* pe_rk = (const float*)d_in[30];
    const float* pe_cq = (const float*)d_in[31];
    const float* pe_ck = (const float*)d_in[32];
    float* out = (float*)d_out;

    char* wsb = (char*)d_ws;
    size_t off = 0;
    auto alloc = [&](size_t bytes) { char* p = wsb + off; off += (bytes + 255) & ~255UL; return p; };
    bf16*  qkv0   = (bf16*) alloc(67108864);    // (8,1024,4096) bf16
    bf16*  qkvpw  = (bf16*) alloc(16777216);    // (8,256,4096) bf16 raw pre-bn
    bf16*  x_t    = (bf16*) alloc(16777216);    // (8,4096,256) bf16
    bf16*  x1a    = (bf16*) alloc(4194304);     // (8,64,4096) bf16
    bf16*  x3a    = (bf16*) alloc(4194304);
    float* rowm   = (float*)alloc(2097152);     // (8,1024,64)
    float* colm   = (float*)alloc(2097152);
    float* atr    = (float*)alloc(1048576);     // (8,512,64)
    float* atc    = (float*)alloc(1048576);
    float* outr   = (float*)alloc(1048576);
    float* outc   = (float*)alloc(1048576);
    float* Wga    = (float*)alloc(1048576);     // (1024,256)
    float* beta   = (float*)alloc(4096);
    bf16*  Nv_t   = (bf16*) alloc(229376);      // (64,1792)
    bf16*  Nh_t   = (bf16*) alloc(229376);
    float* Cv     = (float*)alloc(1792);
    float* Ch     = (float*)alloc(1792);
    bf16*  Mv_t   = (bf16*) alloc(229376);      // (256,448)
    bf16*  Mh_t   = (bf16*) alloc(229376);
    bf16*  Wall   = (bf16*) alloc(524288);      // (1024,256)
    bf16*  wpw_bf = (bf16*) alloc(524288);      // (256,1024)
    bf16*  wproj_bf = (bf16*)alloc(262144);     // (256,512)
    float* sb_s   = (float*)alloc(4096);
    float* sb_b   = (float*)alloc(4096);
    float* kvT2a  = (float*)alloc(1835008);     // (1024,448)
    float* kvT2b  = (float*)alloc(1835008);
    if (off > ws_size) return;

    const long AB = 512L * 64;

    // ---- weight prep ----
    castw<<<2565, 256, 0, stream>>>(wq, wk, wv, sq, sk, sv, bq, bk, bv, w_pw, w_proj,
                                    Wall, wpw_bf, wproj_bf, sb_s, sb_b);
    cast_xt<<<dim3(64, 4, 8), 256, 0, stream>>>(x, x_t);
    build_wga<<<1024, 256, 0, stream>>>(wq, wk, wv, sq, sk, sv, bq, bk, bv, cov_s, cov_b, Wga, beta);
    build_N<<<dim3(448, 2), 256, 0, stream>>>(kv, kv3, Wga, Nv_t, Nh_t);
    build_C<<<dim3(7, 2), 64, 0, stream>>>(kv, kv3, beta, Cv, Ch);
    kv_transpose<<<dim3(1792, 2), 256, 0, stream>>>(kv, kv3, kvT2a, kvT2b);
    build_M2<<<dim3(448, 2), 256, 0, stream>>>(w_pw, kvT2a, kvT2b, Mv_t, Mh_t);

    // ---- qkv0 = bn(1x1 conv) via MFMA ----
    mfma_qkv<<<dim3(32, 8, 8), 256, 0, stream>>>(x_t, Wall, sb_s, sb_b, qkv0);

    // ---- squeeze attention ----
    meanrc<<<8192, 64, 0, stream>>>(qkv0, rowm, colm);
    attn_kernel<<<dim3(8, 8, 2), 256, 0, stream>>>(rowm, colm, pe_rq, pe_rk, pe_cq, pe_ck, atr, atc);
    gemm1x1<<<dim3(1, 8, 8), 256, 0, stream>>>(atr, AB, 0, w_row, s_row, b_row, outr, AB, 0, 512, 512, 64, 1);
    gemm1x1<<<dim3(1, 8, 8), 256, 0, stream>>>(atc, AB, 0, w_col, s_col, b_col, outc, AB, 0, 512, 512, 64, 1);

    // ---- stripe conv 1 + act_dn ----
    mstripe1<<<dim3(16, 8), 256, 0, stream>>>(x_t, Nv_t, Cv, x1a, 0);
    mstripe1<<<dim3(16, 8), 256, 0, stream>>>(x_t, Nh_t, Ch, x3a, 1);
    softmax_sp_bf<<<1024, 256, 0, stream>>>(x1a, x3a);
    group_renorm_bf<<<2048, 256, 0, stream>>>(x1a, x3a);

    // ---- pw conv with fused dw3x3 (bn deferred) + stripe conv 2 via w_pw ----
    mfma_pw_dw<<<dim3(64, 1, 8), 256, 0, stream>>>(qkv0, wpw_bf, w_dw, s_dw, b_dw, qkvpw);
    mstripe2<<<dim3(32, 2, 8), 256, 0, stream>>>(x1a, x3a, Mv_t, Mh_t, qkvpw);

    // ---- final proj with fused epilogue ----
    mfma_proj<<<dim3(32, 2, 8), 256, 0, stream>>>(qkv0, wproj_bf, outr, outc,
                                                  s_proj, b_proj, qkvpw, s_pw, b_pw, out);
}

// Round 7
// 1002.672 us; speedup vs baseline: 1.1113x; 1.0998x over previous
//
#include <hip/hip_runtime.h>
#include <hip/hip_bf16.h>
#include <math.h>

#define HW 4096
typedef __hip_bfloat16 bf16;
typedef __attribute__((ext_vector_type(8))) short bfrag;
typedef __attribute__((ext_vector_type(4))) float ffrag;

__device__ __forceinline__ float bf2f(short u) {
    return __uint_as_float(((unsigned)(unsigned short)u) << 16);
}
__device__ __forceinline__ short f2bfs(float v) {
    bf16 h = __float2bfloat16(v);
    return *reinterpret_cast<short*>(&h);
}

// ======================= cast + transpose x: [256][4096] -> [4096][256] bf16 ==========
__global__ __launch_bounds__(256) void cast_xt(const float* __restrict__ x, bf16* __restrict__ xt)
{
    __shared__ float t[64][65];
    int b = blockIdx.z, it = blockIdx.y, pt = blockIdx.x;
    int ic0 = it * 64, px0 = pt * 64;
    int tid = threadIdx.x;
    for (int l = 0; l < 16; l++) {
        int e = tid + l * 256;
        int px = e & 63, ic = e >> 6;
        t[ic][px] = x[((long)b * 256 + ic0 + ic) * HW + px0 + px];
    }
    __syncthreads();
    for (int l = 0; l < 16; l++) {
        int e = tid + l * 256;
        int ic = e & 63, px = e >> 6;
        xt[((long)b * HW + px0 + px) * 256 + ic0 + ic] = __float2bfloat16(t[ic][px]);
    }
}

// ======================= weight casts ==========
__global__ __launch_bounds__(256) void castw(
    const float* __restrict__ wq, const float* __restrict__ wk, const float* __restrict__ wv,
    const float* __restrict__ sq, const float* __restrict__ sk, const float* __restrict__ sv,
    const float* __restrict__ bq, const float* __restrict__ bk, const float* __restrict__ bv,
    const float* __restrict__ w_pw, const float* __restrict__ w_proj,
    bf16* __restrict__ Wall, bf16* __restrict__ wpw_bf, bf16* __restrict__ wproj_bf,
    float* __restrict__ sb_s, float* __restrict__ sb_b)
{
    int idx = blockIdx.x * 256 + threadIdx.x;
    if (idx < 262144) {
        int oc = idx >> 8, i = idx & 255;
        float v;
        if (oc < 256) v = wq[oc * 256 + i];
        else if (oc < 512) v = wk[(oc - 256) * 256 + i];
        else v = wv[(oc - 512) * 256 + i];
        Wall[idx] = __float2bfloat16(v);
        return;
    }
    idx -= 262144;
    if (idx < 262144) { wpw_bf[idx] = __float2bfloat16(w_pw[idx]); return; }
    idx -= 262144;
    if (idx < 131072) { wproj_bf[idx] = __float2bfloat16(w_proj[idx]); return; }
    idx -= 131072;
    if (idx < 1024) {
        int oc = idx;
        float s, bb;
        if (oc < 256) { s = sq[oc]; bb = bq[oc]; }
        else if (oc < 512) { s = sk[oc - 256]; bb = bk[oc - 256]; }
        else { s = sv[oc - 512]; bb = bv[oc - 512]; }
        sb_s[oc] = s; sb_b[oc] = bb;
    }
}

// ======================= MFMA qkv GEMM (reg-prefetch pipeline) ==========
__global__ __launch_bounds__(256) void mfma_qkv(
    const bf16* __restrict__ Xt, const bf16* __restrict__ Wall,
    const float* __restrict__ sb_s, const float* __restrict__ sb_b,
    bf16* __restrict__ qkv0)
{
    __shared__ __align__(16) short As[128 * 40];
    __shared__ __align__(16) short Bs[128 * 40];
    int b = blockIdx.z, mt = blockIdx.y, nt = blockIdx.x;
    int oc0 = mt * 128, n0 = nt * 128;
    int tid = threadIdx.x;
    int lane = tid & 63, wave = tid >> 6;
    int lr = lane & 15, quad = lane >> 4;
    int wm = (wave & 1) * 64, wn = (wave >> 1) * 64;
    ffrag acc[4][4];
#pragma unroll
    for (int i = 0; i < 4; i++)
#pragma unroll
        for (int j = 0; j < 4; j++)
#pragma unroll
            for (int r = 0; r < 4; r++) acc[i][j][r] = 0.f;

    int4 apf[2], bpf[2];
#pragma unroll
    for (int l = 0; l < 2; l++) {
        int e = tid + l * 256;
        int r = e >> 2, c = e & 3;
        apf[l] = *(const int4*)&Wall[(long)(oc0 + r) * 256 + c * 8];
        bpf[l] = *(const int4*)&Xt[((long)b * HW + n0 + r) * 256 + c * 8];
    }
    for (int s = 0; s < 8; s++) {
        __syncthreads();
#pragma unroll
        for (int l = 0; l < 2; l++) {
            int e = tid + l * 256;
            int r = e >> 2, c = e & 3;
            *(int4*)&As[r * 40 + c * 8] = apf[l];
            *(int4*)&Bs[r * 40 + c * 8] = bpf[l];
        }
        __syncthreads();
        if (s < 7) {
            int k0 = (s + 1) * 32;
#pragma unroll
            for (int l = 0; l < 2; l++) {
                int e = tid + l * 256;
                int r = e >> 2, c = e & 3;
                apf[l] = *(const int4*)&Wall[(long)(oc0 + r) * 256 + k0 + c * 8];
                bpf[l] = *(const int4*)&Xt[((long)b * HW + n0 + r) * 256 + k0 + c * 8];
            }
        }
        bfrag a[4], bb[4];
#pragma unroll
        for (int i = 0; i < 4; i++) a[i]  = *(const bfrag*)&As[(wm + i * 16 + lr) * 40 + quad * 8];
#pragma unroll
        for (int j = 0; j < 4; j++) bb[j] = *(const bfrag*)&Bs[(wn + j * 16 + lr) * 40 + quad * 8];
#pragma unroll
        for (int i = 0; i < 4; i++)
#pragma unroll
            for (int j = 0; j < 4; j++)
                acc[i][j] = __builtin_amdgcn_mfma_f32_16x16x32_bf16(a[i], bb[j], acc[i][j], 0, 0, 0);
    }
#pragma unroll
    for (int i = 0; i < 4; i++)
#pragma unroll
        for (int r = 0; r < 4; r++) {
            int row = oc0 + wm + i * 16 + quad * 4 + r;
            float s = sb_s[row], bb2 = sb_b[row];
#pragma unroll
            for (int j = 0; j < 4; j++) {
                int col = n0 + wn + j * 16 + lr;
                qkv0[((long)b * 1024 + row) * HW + col] = __float2bfloat16(fmaf(s, acc[i][j][r], bb2));
            }
        }
}

// ======================= MFMA pw GEMM, M=256 tile, inline fused dw3x3, XOR-swizzled B ====
// grid (64 y, 1, 8 b); qkvpw[b][256][4096] bf16 (raw pre-bn)
// Inline staging (no cross-iteration prefetch regs -> no scratch spills).
// B LDS row = sigma(px) = (px&7)*8 + ((px>>3)^(px&7)); stride 40 shorts.
__global__ __launch_bounds__(256) void mfma_pw_dw(
    const bf16* __restrict__ qkv0, const bf16* __restrict__ wpw_bf,
    const float* __restrict__ w_dw, const float* __restrict__ s_dw, const float* __restrict__ b_dw,
    bf16* __restrict__ qkvpw)
{
    __shared__ __align__(16) short As[256 * 40];   // 20 KB
    __shared__ __align__(16) short Bst[64 * 40];   // 5 KB
    int b = blockIdx.z, y = blockIdx.x;
    int px0 = y * 64;
    int tid = threadIdx.x;
    int lane = tid & 63, wave = tid >> 6;
    int lr = lane & 15, quad = lane >> 4;
    int wm = wave * 64;
    int dc = tid >> 3;          // 0..31: k within slab
    int ux = tid & 7;           // 0..7:  px group of 8
    int xb = ux * 8;
    ffrag acc[4][4];
#pragma unroll
    for (int i = 0; i < 4; i++)
#pragma unroll
        for (int j = 0; j < 4; j++)
#pragma unroll
            for (int r = 0; r < 4; r++) acc[i][j][r] = 0.f;

    for (int s = 0; s < 32; s++) {
        int k0 = s * 32;
        __syncthreads();
        // ---- A stage (inline) ----
#pragma unroll
        for (int l = 0; l < 4; l++) {
            int e = tid + l * 256;
            int r = e >> 2, c = e & 3;
            *(int4*)&As[r * 40 + c * 8] = *(const int4*)&wpw_bf[(long)r * 1024 + k0 + c * 8];
        }
        // ---- dw3x3 for this 32-ch slab (inline; regs die before MFMA) ----
        {
            int ch = k0 + dc;
            const bf16* base = qkv0 + ((long)b * 1024 + ch) * HW;
            float wd[9];
#pragma unroll
            for (int t = 0; t < 9; t++) wd[t] = w_dw[ch * 9 + t];
            float o8[8];
#pragma unroll
            for (int o = 0; o < 8; o++) o8[o] = 0.f;
#pragma unroll
            for (int dy = 0; dy < 3; dy++) {
                int gr = y + dy - 1;
                if (gr < 0 || gr >= 64) continue;
                short m8[8];
                *(int4*)m8 = *(const int4*)&base[gr * 64 + xb];
                float w10[10];
                w10[0] = (ux > 0) ? bf2f(*(const short*)&base[gr * 64 + xb - 1]) : 0.f;
#pragma unroll
                for (int t = 0; t < 8; t++) w10[t + 1] = bf2f(m8[t]);
                w10[9] = (ux < 7) ? bf2f(*(const short*)&base[gr * 64 + xb + 8]) : 0.f;
#pragma unroll
                for (int dx = 0; dx < 3; dx++) {
                    float wt = wd[dy * 3 + dx];
#pragma unroll
                    for (int o = 0; o < 8; o++)
                        o8[o] = fmaf(wt, w10[o + dx], o8[o]);
                }
            }
            float ss = s_dw[ch], bb0 = b_dw[ch];
#pragma unroll
            for (int o = 0; o < 8; o++)
                Bst[(o * 8 + (ux ^ o)) * 40 + dc] = f2bfs(fmaxf(fmaf(ss, o8[o], bb0), 0.f));
        }
        __syncthreads();
        bfrag a[4], bb[4];
#pragma unroll
        for (int i = 0; i < 4; i++) a[i] = *(const bfrag*)&As[(wm + i * 16 + lr) * 40 + quad * 8];
#pragma unroll
        for (int j = 0; j < 4; j++) {
            int brow = (lr & 7) * 8 + ((j * 2 + (lr >> 3)) ^ (lr & 7));   // sigma(px=j*16+lr)
            bb[j] = *(const bfrag*)&Bst[brow * 40 + quad * 8];
        }
#pragma unroll
        for (int i = 0; i < 4; i++)
#pragma unroll
            for (int j = 0; j < 4; j++)
                acc[i][j] = __builtin_amdgcn_mfma_f32_16x16x32_bf16(a[i], bb[j], acc[i][j], 0, 0, 0);
    }
#pragma unroll
    for (int i = 0; i < 4; i++)
#pragma unroll
        for (int r = 0; r < 4; r++) {
            int row = wm + i * 16 + quad * 4 + r;
#pragma unroll
            for (int j = 0; j < 4; j++) {
                int col = px0 + j * 16 + lr;
                qkvpw[((long)b * 256 + row) * HW + col] = __float2bfloat16(acc[i][j][r]);
            }
        }
}

// ======================= MFMA proj GEMM with fused epilogue, XOR-swizzled B ==========
// B LDS row = sigma7(px) = (px&7)*16 + ((px>>3)^(px&7)); stride 40 shorts.
__global__ __launch_bounds__(256, 2) void mfma_proj(
    const bf16* __restrict__ qkv0, const bf16* __restrict__ wproj_bf,
    const float* __restrict__ outr, const float* __restrict__ outc,
    const float* __restrict__ s_proj, const float* __restrict__ b_proj,
    const bf16* __restrict__ qkvpw, const float* __restrict__ s_pw, const float* __restrict__ b_pw,
    float* __restrict__ out)
{
    __shared__ __align__(16) short As[128 * 40];
    __shared__ __align__(16) short Bst[128 * 40];
    int b = blockIdx.z, mt = blockIdx.y, nt = blockIdx.x;
    int oc0 = mt * 128, y0 = nt * 2, px0 = nt * 128;
    int tid = threadIdx.x;
    int lane = tid & 63, wave = tid >> 6;
    int lr = lane & 15, quad = lane >> 4;
    int wm = (wave & 1) * 64, wn = (wave >> 1) * 64;
    ffrag acc[4][4];
#pragma unroll
    for (int i = 0; i < 4; i++)
#pragma unroll
        for (int j = 0; j < 4; j++)
#pragma unroll
            for (int r = 0; r < 4; r++) acc[i][j][r] = 0.f;

    int4 apf[2], vpf[2];
    float ropf[2]; float4 ocpf[2][2];
#pragma unroll
    for (int l = 0; l < 2; l++) {
        int e = tid + l * 256;
        int r = e >> 2, c4 = e & 3;
        apf[l] = *(const int4*)&wproj_bf[(long)(oc0 + r) * 512 + c4 * 8];
        int cx = e & 15, c = e >> 4;
        vpf[l] = *(const int4*)&qkv0[((long)b * 1024 + 512 + c) * HW + px0 + cx * 8];
        ropf[l] = outr[((long)b * 512 + c) * 64 + y0 + (cx >> 3)];
        const float* cbase = &outc[((long)b * 512 + c) * 64 + (cx & 7) * 8];
        ocpf[l][0] = *(const float4*)&cbase[0];
        ocpf[l][1] = *(const float4*)&cbase[4];
    }
    for (int s = 0; s < 16; s++) {
        __syncthreads();
#pragma unroll
        for (int l = 0; l < 2; l++) {
            int e = tid + l * 256;
            int r = e >> 2, c4 = e & 3;
            *(int4*)&As[r * 40 + c4 * 8] = apf[l];
            int cx = e & 15, c = e >> 4;
            short v8[8];
            *(int4*)v8 = vpf[l];
            float oc8[8];
            *(float4*)&oc8[0] = ocpf[l][0];
            *(float4*)&oc8[4] = ocpf[l][1];
#pragma unroll
            for (int p = 0; p < 8; p++) {
                float val = bf2f(v8[p]) + ropf[l] + oc8[p];
                Bst[(p * 16 + (cx ^ p)) * 40 + c] = f2bfs(fmaxf(val, 0.f));  // sigma7(px=cx*8+p)
            }
        }
        __syncthreads();
        if (s < 15) {
            int k0 = (s + 1) * 32;
#pragma unroll
            for (int l = 0; l < 2; l++) {
                int e = tid + l * 256;
                int r = e >> 2, c4 = e & 3;
                apf[l] = *(const int4*)&wproj_bf[(long)(oc0 + r) * 512 + k0 + c4 * 8];
                int cx = e & 15, c = e >> 4;
                int dh = k0 + c;
                vpf[l] = *(const int4*)&qkv0[((long)b * 1024 + 512 + dh) * HW + px0 + cx * 8];
                ropf[l] = outr[((long)b * 512 + dh) * 64 + y0 + (cx >> 3)];
                const float* cbase = &outc[((long)b * 512 + dh) * 64 + (cx & 7) * 8];
                ocpf[l][0] = *(const float4*)&cbase[0];
                ocpf[l][1] = *(const float4*)&cbase[4];
            }
        }
        bfrag a[4], bb[4];
#pragma unroll
        for (int i = 0; i < 4; i++) a[i] = *(const bfrag*)&As[(wm + i * 16 + lr) * 40 + quad * 8];
#pragma unroll
        for (int j = 0; j < 4; j++) {
            int bidx = (wn >> 3) + j * 2 + (lr >> 3);
            int brow = (lr & 7) * 16 + (bidx ^ (lr & 7));   // sigma7(px=wn+j*16+lr)
            bb[j] = *(const bfrag*)&Bst[brow * 40 + quad * 8];
        }
#pragma unroll
        for (int i = 0; i < 4; i++)
#pragma unroll
            for (int j = 0; j < 4; j++)
                acc[i][j] = __builtin_amdgcn_mfma_f32_16x16x32_bf16(a[i], bb[j], acc[i][j], 0, 0, 0);
    }
#pragma unroll
    for (int i = 0; i < 4; i++)
#pragma unroll
        for (int r = 0; r < 4; r++) {
            int row = oc0 + wm + i * 16 + quad * 4 + r;
            float sp = s_proj[row], bp = b_proj[row];
            float sw = s_pw[row], bw = b_pw[row];
#pragma unroll
            for (int j = 0; j < 4; j++) {
                int col = px0 + wn + j * 16 + lr;
                long idx = ((long)b * 256 + row) * HW + col;
                float t = fmaf(sp, acc[i][j][r], bp);
                float m = fmaf(sw, bf2f(*(const short*)&qkvpw[idx]), bw);
                out[idx] = m / (1.f + __expf(-t));
            }
        }
}

// ======================= MFMA stripe conv 1 (A-prefetch) ==========
__global__ __launch_bounds__(256) void mstripe1(
    const bf16* __restrict__ xt, const bf16* __restrict__ Nt, const float* __restrict__ C,
    bf16* __restrict__ outp, int dir)
{
    __shared__ __align__(16) short As[64 * 264];
    int b = blockIdx.y;
    int tid = threadIdx.x;
    int wave = tid >> 6, lane = tid & 63;
    int lr = lane & 15, quad = lane >> 4;
    int y = blockIdx.x * 4 + wave;
    ffrag acc[4][4];
#pragma unroll
    for (int i = 0; i < 4; i++)
#pragma unroll
        for (int j = 0; j < 4; j++)
#pragma unroll
            for (int r = 0; r < 4; r++) acc[i][j][r] = 0.f;
    bfrag zf;
#pragma unroll
    for (int e = 0; e < 8; e++) zf[e] = 0;

    int4 apf[8];
#pragma unroll
    for (int l = 0; l < 8; l++) {
        int e = tid + l * 256;
        int oc = e >> 5, c = e & 31;
        apf[l] = *(const int4*)&Nt[(long)oc * 1792 + c * 8];
    }
    for (int d = 0; d < 7; d++) {
        __syncthreads();
#pragma unroll
        for (int l = 0; l < 8; l++) {
            int e = tid + l * 256;
            int oc = e >> 5, c = e & 31;
            *(int4*)&As[oc * 264 + c * 8] = apf[l];
        }
        __syncthreads();
        if (d < 6) {
#pragma unroll
            for (int l = 0; l < 8; l++) {
                int e = tid + l * 256;
                int oc = e >> 5, c = e & 31;
                apf[l] = *(const int4*)&Nt[(long)oc * 1792 + (d + 1) * 256 + c * 8];
            }
        }
        int off = d - 3;
        int row = y + off;
        bool vrow = (row >= 0 && row < 64);
        for (int ks = 0; ks < 8; ks++) {
            bfrag a[4], bb[4];
#pragma unroll
            for (int i = 0; i < 4; i++)
                a[i] = *(const bfrag*)&As[(i * 16 + lr) * 264 + ks * 32 + quad * 8];
#pragma unroll
            for (int j = 0; j < 4; j++) {
                int x = j * 16 + lr;
                if (dir == 0) {
                    bb[j] = vrow ? *(const bfrag*)&xt[((long)b * HW + row * 64 + x) * 256 + ks * 32 + quad * 8] : zf;
                } else {
                    int xs = x + off;
                    bb[j] = (xs >= 0 && xs < 64)
                        ? *(const bfrag*)&xt[((long)b * HW + y * 64 + xs) * 256 + ks * 32 + quad * 8] : zf;
                }
            }
#pragma unroll
            for (int i = 0; i < 4; i++)
#pragma unroll
                for (int j = 0; j < 4; j++)
                    acc[i][j] = __builtin_amdgcn_mfma_f32_16x16x32_bf16(a[i], bb[j], acc[i][j], 0, 0, 0);
        }
    }
#pragma unroll
    for (int i = 0; i < 4; i++)
#pragma unroll
        for (int r = 0; r < 4; r++) {
            int oc = i * 16 + quad * 4 + r;
#pragma unroll
            for (int j = 0; j < 4; j++) {
                int x = j * 16 + lr;
                float ct = 0.f;
                int base = dir ? x : y;
                for (int d = 0; d < 7; d++) {
                    int t = base + d - 3;
                    if (t >= 0 && t < 64) ct += C[d * 64 + oc];
                }
                outp[((long)b * 64 + oc) * HW + y * 64 + x] = __float2bfloat16(acc[i][j][r] + ct);
            }
        }
}

// ======================= MFMA stripe conv 2, both dirs, XOR-swizzled B ==========
__device__ __forceinline__ void ms2_load(
    int t, int b, int y0, int oc0, int tid,
    const bf16* __restrict__ x1a, const bf16* __restrict__ x3a,
    const bf16* __restrict__ Mv, const bf16* __restrict__ Mh,
    int4* apf, short bpf[2][8])
{
    int dir = t / 14, rem = t - dir * 14, d = rem >> 1, ks = rem & 1;
    const bf16* inp = dir ? x3a : x1a;
    const bf16* Mt  = dir ? Mh  : Mv;
    int off = d - 3;
#pragma unroll
    for (int l = 0; l < 2; l++) {
        int e = tid + l * 256;
        int r = e >> 2, c4 = e & 3;
        apf[l] = *(const int4*)&Mt[(long)(oc0 + r) * 448 + d * 64 + ks * 32 + c4 * 8];
        int cx = e & 15, c = e >> 4;
        int ic = ks * 32 + c;
        const bf16* src = &inp[((long)b * 64 + ic) * HW];
        if (dir == 0) {
            int srow = y0 + (cx >> 3) + off;
            if (srow >= 0 && srow < 64)
                *(int4*)bpf[l] = *(const int4*)&src[srow * 64 + (cx & 7) * 8];
            else {
                int4 z = {0,0,0,0};
                *(int4*)bpf[l] = z;
            }
        } else {
            int row = y0 + (cx >> 3);
#pragma unroll
            for (int p = 0; p < 8; p++) {
                int xs = (cx & 7) * 8 + p + off;
                bpf[l][p] = (xs >= 0 && xs < 64) ? *(const short*)&src[row * 64 + xs] : (short)0;
            }
        }
    }
}

__global__ __launch_bounds__(256, 2) void mstripe2(
    const bf16* __restrict__ x1a, const bf16* __restrict__ x3a,
    const bf16* __restrict__ Mv, const bf16* __restrict__ Mh,
    bf16* __restrict__ qkvpw)
{
    __shared__ __align__(16) short As[128 * 40];
    __shared__ __align__(16) short Bst[128 * 40];
    int b = blockIdx.z, mt = blockIdx.y, nt = blockIdx.x;
    int oc0 = mt * 128, y0 = nt * 2, px0 = nt * 128;
    int tid = threadIdx.x;
    int lane = tid & 63, wave = tid >> 6;
    int lr = lane & 15, quad = lane >> 4;
    int wm = (wave & 1) * 64, wn = (wave >> 1) * 64;
    ffrag acc[4][4];
#pragma unroll
    for (int i = 0; i < 4; i++)
#pragma unroll
        for (int j = 0; j < 4; j++)
#pragma unroll
            for (int r = 0; r < 4; r++) acc[i][j][r] = 0.f;

    int4 apf[2]; short bpf[2][8];
    ms2_load(0, b, y0, oc0, tid, x1a, x3a, Mv, Mh, apf, bpf);
    for (int t = 0; t < 28; t++) {
        __syncthreads();
#pragma unroll
        for (int l = 0; l < 2; l++) {
            int e = tid + l * 256;
            int r = e >> 2, c4 = e & 3;
            *(int4*)&As[r * 40 + c4 * 8] = apf[l];
            int cx = e & 15, c = e >> 4;
#pragma unroll
            for (int p = 0; p < 8; p++)
                Bst[(p * 16 + (cx ^ p)) * 40 + c] = bpf[l][p];   // sigma7
        }
        __syncthreads();
        if (t < 27)
            ms2_load(t + 1, b, y0, oc0, tid, x1a, x3a, Mv, Mh, apf, bpf);
        bfrag a[4], bb[4];
#pragma unroll
        for (int i = 0; i < 4; i++) a[i] = *(const bfrag*)&As[(wm + i * 16 + lr) * 40 + quad * 8];
#pragma unroll
        for (int j = 0; j < 4; j++) {
            int bidx = (wn >> 3) + j * 2 + (lr >> 3);
            int brow = (lr & 7) * 16 + (bidx ^ (lr & 7));
            bb[j] = *(const bfrag*)&Bst[brow * 40 + quad * 8];
        }
#pragma unroll
        for (int i = 0; i < 4; i++)
#pragma unroll
            for (int j = 0; j < 4; j++)
                acc[i][j] = __builtin_amdgcn_mfma_f32_16x16x32_bf16(a[i], bb[j], acc[i][j], 0, 0, 0);
    }
#pragma unroll
    for (int i = 0; i < 4; i++)
#pragma unroll
        for (int r = 0; r < 4; r++) {
            int row = oc0 + wm + i * 16 + quad * 4 + r;
#pragma unroll
            for (int j = 0; j < 4; j++) {
                int col = px0 + wn + j * 16 + lr;
                long idx = ((long)b * 256 + row) * HW + col;
                float v = bf2f(*(const short*)&qkvpw[idx]) + acc[i][j][r];
                qkvpw[idx] = __float2bfloat16(v);
            }
        }
}

// ======================= act_dn (bf16, register-resident, both tensors) ==========
__global__ __launch_bounds__(256) void softmax_sp_bf(bf16* __restrict__ x1, bf16* __restrict__ x3)
{
    __shared__ float red[4];
    int bc = blockIdx.x;   // 0..1023
    bf16* p = (bc < 512) ? (x1 + (long)bc * HW) : (x3 + (long)(bc - 512) * HW);
    int tid = threadIdx.x;
    float v[16];
#pragma unroll
    for (int i = 0; i < 16; i++) v[i] = __bfloat162float(p[tid + i * 256]);
    float m = -1e30f;
#pragma unroll
    for (int i = 0; i < 16; i++) m = fmaxf(m, v[i]);
    for (int o = 32; o > 0; o >>= 1) m = fmaxf(m, __shfl_down(m, o));
    if ((tid & 63) == 0) red[tid >> 6] = m;
    __syncthreads();
    m = fmaxf(fmaxf(red[0], red[1]), fmaxf(red[2], red[3]));
    __syncthreads();
    float z = 0.f;
#pragma unroll
    for (int i = 0; i < 16; i++) { v[i] = __expf(v[i] - m); z += v[i]; }
    for (int o = 32; o > 0; o >>= 1) z += __shfl_down(z, o);
    if ((tid & 63) == 0) red[tid >> 6] = z;
    __syncthreads();
    z = red[0] + red[1] + red[2] + red[3];
    float inv = 1.f / z;
#pragma unroll
    for (int i = 0; i < 16; i++) p[tid + i * 256] = __float2bfloat16(v[i] * inv);
}

__global__ __launch_bounds__(256) void group_renorm_bf(bf16* __restrict__ x1, bf16* __restrict__ x3)
{
    int which = blockIdx.x >> 10;
    long t = (long)(blockIdx.x & 1023) * 256 + threadIdx.x;   // B*8*4096
    bf16* x = which ? x3 : x1;
    int s = (int)(t & 4095);
    int h = (int)((t >> 12) & 7);
    int b = (int)(t >> 15);
    bf16* base = x + (((long)(b * 64 + h * 8)) << 12) + s;
    float v[8]; float g = 0.f;
#pragma unroll
    for (int j = 0; j < 8; j++) { v[j] = __bfloat162float(base[(long)j << 12]); g += v[j]; }
    float inv = 1.f / (g + 1e-6f);
#pragma unroll
    for (int j = 0; j < 8; j++) base[(long)j << 12] = __float2bfloat16(v[j] * inv);
}

// ======================= row/col means of qkv0 (bf16) =======================
__global__ __launch_bounds__(64) void meanrc(
    const bf16* __restrict__ in, float* __restrict__ rowm, float* __restrict__ colm)
{
    __shared__ float tile[64][65];
    int bc = blockIdx.x;
    const bf16* p = in + (long)bc * HW;
    int t = threadIdx.x;
    for (int i = 0; i < 64; i++) tile[i][t] = __bfloat162float(p[i * 64 + t]);
    __syncthreads();
    float rs = 0.f, cs = 0.f;
    for (int i = 0; i < 64; i++) { rs += tile[t][i]; cs += tile[i][t]; }
    rowm[(long)bc * 64 + t] = rs * (1.f / 64.f);
    colm[(long)bc * 64 + t] = cs * (1.f / 64.f);
}

// ======================= squeeze attention =======================
__device__ __forceinline__ float interp_pe(const float* pe, int c, int i)
{
    float coord = fminf(fmaxf((i + 0.5f) * 0.25f - 0.5f, 0.f), 15.f);
    int lo = (int)coord;
    int hi = min(lo + 1, 15);
    float t = coord - (float)lo;
    return pe[c * 16 + lo] * (1.f - t) + pe[c * 16 + hi] * t;
}

__global__ __launch_bounds__(256) void attn_kernel(
    const float* __restrict__ rowm, const float* __restrict__ colm,
    const float* __restrict__ pe_rq, const float* __restrict__ pe_rk,
    const float* __restrict__ pe_cq, const float* __restrict__ pe_ck,
    float* __restrict__ outr, float* __restrict__ outc)
{
    int h = blockIdx.x, b = blockIdx.y, dir = blockIdx.z;
    const float* mean = dir ? colm : rowm;
    const float* peq = dir ? pe_cq : pe_rq;
    const float* pek = dir ? pe_ck : pe_rk;
    float* outp = (dir ? outc : outr) + ((long)b * 512 + h * 64) * 64;
    __shared__ float qs[32][64], ks[32][64], vs[64][64], S[64][66];
    int tid = threadIdx.x;

    for (int e = tid; e < 2048; e += 256) {
        int c = e >> 6, i = e & 63;
        int gc = h * 32 + c;
        qs[c][i] = mean[((long)b * 1024 + gc) * 64 + i]       + interp_pe(peq, gc, i);
        ks[c][i] = mean[((long)b * 1024 + 256 + gc) * 64 + i] + interp_pe(pek, gc, i);
    }
    for (int e = tid; e < 4096; e += 256) {
        int dc = e >> 6, j = e & 63;
        vs[dc][j] = mean[((long)b * 1024 + 512 + h * 64 + dc) * 64 + j];
    }
    __syncthreads();
    const float scl = 0.17677669529663687f;
    for (int e = tid; e < 4096; e += 256) {
        int i = e >> 6, j = e & 63;
        float s = 0.f;
#pragma unroll
        for (int c = 0; c < 32; c++) s = fmaf(qs[c][i], ks[c][j], s);
        S[i][j] = s * scl;
    }
    __syncthreads();
    if (tid < 64) {
        int i = tid;
        float m = -1e30f;
        for (int j = 0; j < 64; j++) m = fmaxf(m, S[i][j]);
        float z = 0.f;
        for (int j = 0; j < 64; j++) { float e2 = __expf(S[i][j] - m); S[i][j] = e2; z += e2; }
        float inv = 1.f / z;
        for (int j = 0; j < 64; j++) S[i][j] *= inv;
    }
    __syncthreads();
    for (int e = tid; e < 4096; e += 256) {
        int dc = e >> 6, i = e & 63;
        float o = 0.f;
#pragma unroll
        for (int j = 0; j < 64; j++) o = fmaf(S[i][j], vs[dc][j], o);
        outp[dc * 64 + i] = o;
    }
}

// ======================= small fp32 GEMM (row/col attention projections) ==========
__global__ __launch_bounds__(256) void gemm1x1(
    const void* __restrict__ X, long x_b, int in_bf16,
    const float* __restrict__ W,
    const float* __restrict__ scale, const float* __restrict__ bias,
    void* __restrict__ out, long o_b, int out_bf16,
    int OC, int IC, int NP,
    int relu_in)
{
    __shared__ __align__(16) float As[16][68];
    __shared__ __align__(16) float Bs[16][64];
    int b  = blockIdx.z;
    int oc0 = blockIdx.y * 64;
    int n0  = blockIdx.x * 64;
    int tid = threadIdx.x;
    int tx = tid & 15, ty = tid >> 4;
    float acc[4][4] = {};

    for (int k0 = 0; k0 < IC; k0 += 16) {
#pragma unroll
        for (int l = 0; l < 4; l++) {
            int e = tid + l * 256;
            int oc = e >> 4, kk = e & 15;
            As[kk][oc] = W[(long)(oc0 + oc) * IC + (k0 + kk)];
        }
#pragma unroll
        for (int l = 0; l < 4; l++) {
            int e = tid + l * 256;
            int kk = e >> 6, n = e & 63;
            int ic = k0 + kk;
            long xi = (long)b * x_b + (long)ic * NP + (n0 + n);
            float v = in_bf16 ? __bfloat162float(((const bf16*)X)[xi])
                              : ((const float*)X)[xi];
            if (relu_in) v = fmaxf(v, 0.f);
            Bs[kk][n] = v;
        }
        __syncthreads();
#pragma unroll
        for (int kk = 0; kk < 16; kk++) {
            float a[4], bv[4];
            *(float4*)a  = *(const float4*)&As[kk][ty * 4];
            *(float4*)bv = *(const float4*)&Bs[kk][tx * 4];
#pragma unroll
            for (int i = 0; i < 4; i++)
#pragma unroll
                for (int j = 0; j < 4; j++)
                    acc[i][j] = fmaf(a[i], bv[j], acc[i][j]);
        }
        __syncthreads();
    }

#pragma unroll
    for (int i = 0; i < 4; i++) {
        int oc = oc0 + ty * 4 + i;
        float s  = scale ? scale[oc] : 1.f;
        float bb = bias  ? bias[oc]  : 0.f;
#pragma unroll
        for (int j = 0; j < 4; j++) {
            int n = n0 + tx * 4 + j;
            float v = fmaf(s, acc[i][j], bb);
            long oidx = (long)b * o_b + (long)oc * NP + n;
            if (out_bf16) ((bf16*)out)[oidx] = __float2bfloat16(v);
            else          ((float*)out)[oidx] = v;
        }
    }
}

// ======================= weight pre-contraction =======================
__global__ __launch_bounds__(256) void build_wga(
    const float* __restrict__ wq, const float* __restrict__ wk, const float* __restrict__ wv,
    const float* __restrict__ sq, const float* __restrict__ sk, const float* __restrict__ sv,
    const float* __restrict__ bq, const float* __restrict__ bk, const float* __restrict__ bv,
    const float* __restrict__ cov_s, const float* __restrict__ cov_b,
    float* __restrict__ Wga, float* __restrict__ beta)
{
    int idx = blockIdx.x * 256 + threadIdx.x;
    int ic = idx >> 8, i = idx & 255;
    const float* Wp; float sth, bth;
    if (ic < 256)      { Wp = wq + ic * 256;         sth = sq[ic];       bth = bq[ic]; }
    else if (ic < 512) { Wp = wk + (ic - 256) * 256; sth = sk[ic - 256]; bth = bk[ic - 256]; }
    else               { Wp = wv + (ic - 512) * 256; sth = sv[ic - 512]; bth = bv[ic - 512]; }
    Wga[idx] = cov_s[ic] * sth * Wp[i];
    if (i == 0) beta[ic] = cov_s[ic] * bth + cov_b[ic];
}

// N_t[oc][d*256 + i] = sum_ic kv[oc, ic, d] * Wga[ic, i] ; grid (448, 2)
__global__ __launch_bounds__(256) void build_N(
    const float* __restrict__ kva, const float* __restrict__ kvb,
    const float* __restrict__ Wga, bf16* __restrict__ Nta, bf16* __restrict__ Ntb)
{
    const float* kvw = blockIdx.y ? kvb : kva;
    bf16* Nt = blockIdx.y ? Ntb : Nta;
    int d = blockIdx.x >> 6, oc = blockIdx.x & 63;
    int i = threadIdx.x;
    float a0 = 0.f, a1 = 0.f, a2 = 0.f, a3 = 0.f;
    for (int ic = 0; ic < 1024; ic += 4) {
        a0 = fmaf(kvw[oc * 7168 + ic * 7 + d],           Wga[ic * 256 + i],           a0);
        a1 = fmaf(kvw[oc * 7168 + (ic + 1) * 7 + d],     Wga[(ic + 1) * 256 + i],     a1);
        a2 = fmaf(kvw[oc * 7168 + (ic + 2) * 7 + d],     Wga[(ic + 2) * 256 + i],     a2);
        a3 = fmaf(kvw[oc * 7168 + (ic + 3) * 7 + d],     Wga[(ic + 3) * 256 + i],     a3);
    }
    Nt[(long)oc * 1792 + d * 256 + i] = __float2bfloat16((a0 + a1) + (a2 + a3));
}

// grid (7, 2)
__global__ __launch_bounds__(64) void build_C(
    const float* __restrict__ kva, const float* __restrict__ kvb,
    const float* __restrict__ beta, float* __restrict__ Ca, float* __restrict__ Cb)
{
    const float* kvw = blockIdx.y ? kvb : kva;
    float* C = blockIdx.y ? Cb : Ca;
    int d = blockIdx.x, oc = threadIdx.x;
    float a = 0.f;
    for (int ic = 0; ic < 1024; ic++)
        a = fmaf(kvw[oc * 7168 + ic * 7 + d], beta[ic], a);
    C[d * 64 + oc] = a;
}

// kvT2[c2][d*64+ic] = kv[ic][c2][d] ; grid (1792, 2)
__global__ __launch_bounds__(256) void kv_transpose(
    const float* __restrict__ kva, const float* __restrict__ kvb,
    float* __restrict__ kvT2a, float* __restrict__ kvT2b)
{
    const float* kvw = blockIdx.y ? kvb : kva;
    float* kvT2 = blockIdx.y ? kvT2b : kvT2a;
    int idx = blockIdx.x * 256 + threadIdx.x;
    if (idx >= 458752) return;
    int c2 = idx / 448;
    int rem = idx - c2 * 448;
    int d = rem >> 6, ic = rem & 63;
    kvT2[idx] = kvw[ic * 7168 + c2 * 7 + d];
}

// M_t[o][d*64 + ic] = sum_c2 wpw[o][c2] * kvT2[c2][d*64+ic] ; grid (448, 2)
__global__ __launch_bounds__(256) void build_M2(
    const float* __restrict__ wpw,
    const float* __restrict__ kvT2a, const float* __restrict__ kvT2b,
    bf16* __restrict__ Mta, bf16* __restrict__ Mtb)
{
    const float* kvT2 = blockIdx.y ? kvT2b : kvT2a;
    bf16* Mt = blockIdx.y ? Mtb : Mta;
    int d = blockIdx.x % 7, og = blockIdx.x / 7;
    int o = og * 4 + (threadIdx.x >> 6);
    int ic = threadIdx.x & 63;
    const float* kp = kvT2 + d * 64 + ic;
    const float* wp = wpw + (long)o * 1024;
    float a0 = 0.f, a1 = 0.f, a2 = 0.f, a3 = 0.f;
    for (int c2 = 0; c2 < 1024; c2 += 4) {
        a0 = fmaf(wp[c2],     kp[(long)c2 * 448],       a0);
        a1 = fmaf(wp[c2 + 1], kp[(long)(c2 + 1) * 448], a1);
        a2 = fmaf(wp[c2 + 2], kp[(long)(c2 + 2) * 448], a2);
        a3 = fmaf(wp[c2 + 3], kp[(long)(c2 + 3) * 448], a3);
    }
    Mt[(long)o * 448 + d * 64 + ic] = __float2bfloat16((a0 + a1) + (a2 + a3));
}

// ======================= launch =======================
extern "C" void kernel_launch(void* const* d_in, const int* in_sizes, int n_in,
                              void* d_out, int out_size, void* d_ws, size_t ws_size,
                              hipStream_t stream)
{
    const float* x     = (const float*)d_in[0];
    const float* wq    = (const float*)d_in[1];
    const float* sq    = (const float*)d_in[2];
    const float* bq    = (const float*)d_in[3];
    const float* wk    = (const float*)d_in[4];
    const float* sk    = (const float*)d_in[5];
    const float* bk    = (const float*)d_in[6];
    const float* wv    = (const float*)d_in[7];
    const float* sv    = (const float*)d_in[8];
    const float* bv    = (const float*)d_in[9];
    const float* w_dw  = (const float*)d_in[10];
    const float* s_dw  = (const float*)d_in[11];
    const float* b_dw  = (const float*)d_in[12];
    const float* cov_s = (const float*)d_in[13];
    const float* cov_b = (const float*)d_in[14];
    const float* kv    = (const float*)d_in[15];
    const float* kv3   = (const float*)d_in[16];
    const float* w_pw  = (const float*)d_in[17];
    const float* s_pw  = (const float*)d_in[18];
    const float* b_pw  = (const float*)d_in[19];
    const float* w_row = (const float*)d_in[20];
    const float* s_row = (const float*)d_in[21];
    const float* b_row = (const float*)d_in[22];
    const float* w_col = (const float*)d_in[23];
    const float* s_col = (const float*)d_in[24];
    const float* b_col = (const float*)d_in[25];
    const float* w_proj= (const float*)d_in[26];
    const float* s_proj= (const float*)d_in[27];
    const float* b_proj= (const float*)d_in[28];
    const float* pe_rq = (const float*)d_in[29];
    const float* pe_rk = (const float*)d_in[30];
    const float* pe_cq = (const float*)d_in[31];
    const float* pe_ck = (const float*)d_in[32];
    float* out = (float*)d_out;

    char* wsb = (char*)d_ws;
    size_t off = 0;
    auto alloc = [&](size_t bytes) { char* p = wsb + off; off += (bytes + 255) & ~255UL; return p; };
    bf16*  qkv0   = (bf16*) alloc(67108864);    // (8,1024,4096) bf16
    bf16*  qkvpw  = (bf16*) alloc(16777216);    // (8,256,4096) bf16 raw pre-bn
    bf16*  x_t    = (bf16*) alloc(16777216);    // (8,4096,256) bf16
    bf16*  x1a    = (bf16*) alloc(4194304);     // (8,64,4096) bf16
    bf16*  x3a    = (bf16*) alloc(4194304);
    float* rowm   = (float*)alloc(2097152);     // (8,1024,64)
    float* colm   = (float*)alloc(2097152);
    float* atr    = (float*)alloc(1048576);     // (8,512,64)
    float* atc    = (float*)alloc(1048576);
    float* outr   = (float*)alloc(1048576);
    float* outc   = (float*)alloc(1048576);
    float* Wga    = (float*)alloc(1048576);     // (1024,256)
    float* beta   = (float*)alloc(4096);
    bf16*  Nv_t   = (bf16*) alloc(229376);      // (64,1792)
    bf16*  Nh_t   = (bf16*) alloc(229376);
    float* Cv     = (float*)alloc(1792);
    float* Ch     = (float*)alloc(1792);
    bf16*  Mv_t   = (bf16*) alloc(229376);      // (256,448)
    bf16*  Mh_t   = (bf16*) alloc(229376);
    bf16*  Wall   = (bf16*) alloc(524288);      // (1024,256)
    bf16*  wpw_bf = (bf16*) alloc(524288);      // (256,1024)
    bf16*  wproj_bf = (bf16*)alloc(262144);     // (256,512)
    float* sb_s   = (float*)alloc(4096);
    float* sb_b   = (float*)alloc(4096);
    float* kvT2a  = (float*)alloc(1835008);     // (1024,448)
    float* kvT2b  = (float*)alloc(1835008);
    if (off > ws_size) return;

    const long AB = 512L * 64;

    // ---- weight prep ----
    castw<<<2565, 256, 0, stream>>>(wq, wk, wv, sq, sk, sv, bq, bk, bv, w_pw, w_proj,
                                    Wall, wpw_bf, wproj_bf, sb_s, sb_b);
    cast_xt<<<dim3(64, 4, 8), 256, 0, stream>>>(x, x_t);
    build_wga<<<1024, 256, 0, stream>>>(wq, wk, wv, sq, sk, sv, bq, bk, bv, cov_s, cov_b, Wga, beta);
    build_N<<<dim3(448, 2), 256, 0, stream>>>(kv, kv3, Wga, Nv_t, Nh_t);
    build_C<<<dim3(7, 2), 64, 0, stream>>>(kv, kv3, beta, Cv, Ch);
    kv_transpose<<<dim3(1792, 2), 256, 0, stream>>>(kv, kv3, kvT2a, kvT2b);
    build_M2<<<dim3(448, 2), 256, 0, stream>>>(w_pw, kvT2a, kvT2b, Mv_t, Mh_t);

    // ---- qkv0 = bn(1x1 conv) via MFMA ----
    mfma_qkv<<<dim3(32, 8, 8), 256, 0, stream>>>(x_t, Wall, sb_s, sb_b, qkv0);

    // ---- squeeze attention ----
    meanrc<<<8192, 64, 0, stream>>>(qkv0, rowm, colm);
    attn_kernel<<<dim3(8, 8, 2), 256, 0, stream>>>(rowm, colm, pe_rq, pe_rk, pe_cq, pe_ck, atr, atc);
    gemm1x1<<<dim3(1, 8, 8), 256, 0, stream>>>(atr, AB, 0, w_row, s_row, b_row, outr, AB, 0, 512, 512, 64, 1);
    gemm1x1<<<dim3(1, 8, 8), 256, 0, stream>>>(atc, AB, 0, w_col, s_col, b_col, outc, AB, 0, 512, 512, 64, 1);

    // ---- stripe conv 1 + act_dn ----
    mstripe1<<<dim3(16, 8), 256, 0, stream>>>(x_t, Nv_t, Cv, x1a, 0);
    mstripe1<<<dim3(16, 8), 256, 0, stream>>>(x_t, Nh_t, Ch, x3a, 1);
    softmax_sp_bf<<<1024, 256, 0, stream>>>(x1a, x3a);
    group_renorm_bf<<<2048, 256, 0, stream>>>(x1a, x3a);

    // ---- pw conv with fused dw3x3 (bn deferred) + stripe conv 2 via w_pw ----
    mfma_pw_dw<<<dim3(64, 1, 8), 256, 0, stream>>>(qkv0, wpw_bf, w_dw, s_dw, b_dw, qkvpw);
    mstripe2<<<dim3(32, 2, 8), 256, 0, stream>>>(x1a, x3a, Mv_t, Mh_t, qkvpw);

    // ---- final proj with fused epilogue ----
    mfma_proj<<<dim3(32, 2, 8), 256, 0, stream>>>(qkv0, wproj_bf, outr, outc,
                                                  s_proj, b_proj, qkvpw, s_pw, b_pw, out);
}